// Round 4
// baseline (262.656 us; speedup 1.0000x reference)
//
#include <hip/hip_runtime.h>

typedef unsigned short u16;
typedef __bf16 bf16x8 __attribute__((ext_vector_type(8)));
typedef float f32x4 __attribute__((ext_vector_type(4)));

// ---- problem constants ----
constexpr int SEQ = 2048;
constexpr int HIDN = 2880;
constexpr int NQKV = 5120;   // 4096 q | 512 k | 512 v
constexpr float SCALE = 0.125f;   // 1/sqrt(64)
constexpr float NEG_INF = -1e30f;

#define ASM_VMCNT(n)  asm volatile("s_waitcnt vmcnt(" #n ")" ::: "memory")
#define ASM_LGKM(n)   asm volatile("s_waitcnt lgkmcnt(" #n ")" ::: "memory")
#define ASM_BARRIER() asm volatile("s_barrier" ::: "memory")
#define SCHEDBAR()    __builtin_amdgcn_sched_barrier(0)

__device__ __forceinline__ u16 f2bf(float f) {
  unsigned int u = __builtin_bit_cast(unsigned int, f);
  u += 0x7FFFu + ((u >> 16) & 1u);
  return (u16)(u >> 16);
}
__device__ __forceinline__ float bf2f(u16 h) {
  unsigned int u = ((unsigned int)h) << 16;
  return __builtin_bit_cast(float, u);
}
__device__ __forceinline__ void async_load16(const void* g, void* l) {
  __builtin_amdgcn_global_load_lds(
      (const __attribute__((address_space(1))) unsigned int*)g,
      (__attribute__((address_space(3))) unsigned int*)l, 16, 0, 0);
}
// asm ds_read_b128: opaque to compiler mem-dep tracking; ordering enforced
// by the volatile waitcnt fences + sched_barrier (rule #18).
__device__ __forceinline__ f32x4 DSR(unsigned addr) {
  f32x4 d;
  asm volatile("ds_read_b128 %0, %1" : "=v"(d) : "v"(addr));
  return d;
}
__device__ __forceinline__ bf16x8 asbf(f32x4 v) { return __builtin_bit_cast(bf16x8, v); }

// ---- fp32 -> bf16 flat convert ----
__global__ __launch_bounds__(256) void conv_f2b(const float* __restrict__ in,
                                                u16* __restrict__ out, long n4) {
  long i = (long)blockIdx.x * 256 + threadIdx.x;
  if (i >= n4) return;
  float4 v = ((const float4*)in)[i];
  u16 o0 = f2bf(v.x), o1 = f2bf(v.y), o2 = f2bf(v.z), o3 = f2bf(v.w);
  out[i * 4 + 0] = o0; out[i * 4 + 1] = o1; out[i * 4 + 2] = o2; out[i * 4 + 3] = o3;
}

// ---- fp32 [R][C] -> bf16 out[c][r] (transpose-convert), dims % 32 == 0 ----
__global__ __launch_bounds__(256) void transpose_f2b(const float* __restrict__ in,
                                                     u16* __restrict__ out,
                                                     int R, int C, int ostride) {
  __shared__ float tile[32][33];
  int c0 = blockIdx.x * 32, r0 = blockIdx.y * 32;
  int tx = threadIdx.x & 31, ty = threadIdx.x >> 5;
#pragma unroll
  for (int i = 0; i < 32; i += 8)
    tile[ty + i][tx] = in[(long)(r0 + ty + i) * C + c0 + tx];
  __syncthreads();
#pragma unroll
  for (int i = 0; i < 32; i += 8)
    out[(long)(c0 + ty + i) * ostride + r0 + tx] = f2bf(tile[tx][ty + i]);
}

__global__ __launch_bounds__(256) void concat_bias(const float* bq, const float* bk,
                                                   const float* bv, float* out) {
  int t = blockIdx.x * 256 + threadIdx.x;
  if (t < 4096) out[t] = bq[t];
  else if (t < 4608) out[t] = bk[t - 4096];
  else if (t < 5120) out[t] = bv[t - 4608];
}

// ======== unified GEMM: C[M][N] = A[M][K] @ B_t[N][K]^T + bias ========
// BM=128, BN=256, BK=32; 256 thr = 4 waves (1M x 4N), per-wave 128x64.
// Triple-buffered 24KB tiles (72KB -> 2 blocks/CU); T2 slot-XOR swizzle
// (source-side); stage lead 2; vmcnt(12); lgkm-split MFMA overlap;
// end-barrier closes WAR on buf(t-1); T1 XCD swizzle; T5 setprio.
template <bool OUT_BF16>
__global__ __launch_bounds__(256, 2) void gemm_kb(const u16* __restrict__ A,
                                                  const u16* __restrict__ B,
                                                  const float* __restrict__ bias,
                                                  void* __restrict__ Cout,
                                                  int N, int K) {
  __shared__ u16 lds[3 * 12288];  // per buf: A[128][32] 8KB | B[256][32] 16KB
  const int tid = threadIdx.x, lane = tid & 63, wn = tid >> 6;
  const int lr = lane & 15, lk = lane >> 4;

  // T1: bijective XCD swizzle
  const int gm = gridDim.x;
  int nwg = gm * gridDim.y;
  int bid = blockIdx.y * gm + blockIdx.x;
  int q8 = nwg >> 3, r8 = nwg & 7;
  int xcd = bid & 7, seq = bid >> 3;
  int swz = (xcd < r8 ? xcd * (q8 + 1) : r8 * (q8 + 1) + (xcd - r8) * q8) + seq;
  const long brow = (long)(swz % gm) * 128;
  const long bcol = (long)(swz / gm) * 256;
  const int nkt = K >> 5;

  // staging sources, pre-swizzled: chunk c -> row c>>2, phys slot c&3,
  // logical slot = (c&3) ^ ((row>>1)&3) = (c&3) ^ ((c>>3)&3)
  const int ca0 = tid, ca1 = tid + 256;
  const u16* As0 = A + (brow + (ca0 >> 2)) * (long)K + ((ca0 & 3) ^ ((ca0 >> 3) & 3)) * 8;
  const u16* As1 = A + (brow + (ca1 >> 2)) * (long)K + ((ca1 & 3) ^ ((ca1 >> 3) & 3)) * 8;
  const u16* Bsr[4];
#pragma unroll
  for (int i = 0; i < 4; ++i) {
    int c = tid + 256 * i;
    Bsr[i] = B + (bcol + (c >> 2)) * (long)K + ((c & 3) ^ ((c >> 3) & 3)) * 8;
  }
  char* L = (char*)lds;
  auto stage = [&](int kt, int b) {
    long ko = (long)kt * 32;
    char* d = L + b * 24576;
    async_load16(As0 + ko, d + ca0 * 16);
    async_load16(As1 + ko, d + ca1 * 16);
#pragma unroll
    for (int i = 0; i < 4; ++i)
      async_load16(Bsr[i] + ko, d + 8192 + (tid + 256 * i) * 16);
  };

  // read offsets: row*64 + (lk ^ ((lr>>1)&3))*16  (2-way, free — R2-verified)
  const unsigned lds0 = (unsigned)(size_t)L;
  const unsigned xs = (unsigned)((lk ^ ((lr >> 1) & 3)) << 4);
  const unsigned aoff = lds0 + (unsigned)(lr * 64) + xs;                   // + m*1024
  const unsigned boff = lds0 + 8192u + (unsigned)((wn * 64 + lr) * 64) + xs;  // + n*1024

  f32x4 acc[8][4] = {};
  stage(0, 0);
  if (nkt > 1) stage(1, 1);

  int b = 0, sb = 2;
  for (int t = 0; t < nkt; ++t) {
    // prefetch + counted wait ensuring stage(t) landed (ledger: outstanding
    // after issue = stage(t+1)+stage(t+2) = 12)
    if (t + 2 < nkt)      { stage(t + 2, sb); ASM_VMCNT(12); }
    else if (t + 1 < nkt) { ASM_VMCNT(6); }
    else                  { ASM_VMCNT(0); }
    ASM_BARRIER();

    const unsigned ab = aoff + (unsigned)(b * 24576);
    const unsigned bb = boff + (unsigned)(b * 24576);
    f32x4 af[8], bf4[4];
#pragma unroll
    for (int m = 0; m < 4; ++m) af[m] = DSR(ab + m * 1024u);
#pragma unroll
    for (int n = 0; n < 4; ++n) bf4[n] = DSR(bb + n * 1024u);
#pragma unroll
    for (int m = 4; m < 8; ++m) af[m] = DSR(ab + m * 1024u);
    ASM_LGKM(4); SCHEDBAR();      // first 8 reads done; A4-7 still in flight
    __builtin_amdgcn_s_setprio(1);
#pragma unroll
    for (int m = 0; m < 4; ++m)
#pragma unroll
      for (int n = 0; n < 4; ++n)
        acc[m][n] = __builtin_amdgcn_mfma_f32_16x16x32_bf16(asbf(af[m]), asbf(bf4[n]), acc[m][n], 0, 0, 0);
    __builtin_amdgcn_s_setprio(0);
    ASM_LGKM(0); SCHEDBAR();
    __builtin_amdgcn_s_setprio(1);
#pragma unroll
    for (int m = 4; m < 8; ++m)
#pragma unroll
      for (int n = 0; n < 4; ++n)
        acc[m][n] = __builtin_amdgcn_mfma_f32_16x16x32_bf16(asbf(af[m]), asbf(bf4[n]), acc[m][n], 0, 0, 0);
    __builtin_amdgcn_s_setprio(0);
    ASM_BARRIER();                // WAR: all lgkm0 done before next stage hits buf(t-1)
    b = (b == 2) ? 0 : b + 1;
    sb = (sb == 2) ? 0 : sb + 1;
  }

#pragma unroll
  for (int m = 0; m < 8; ++m) {
    long row = brow + m * 16 + lk * 4;
#pragma unroll
    for (int n = 0; n < 4; ++n) {
      long col = bcol + wn * 64 + n * 16 + lr;
      if (col < N) {
        float bv = bias[col];
#pragma unroll
        for (int r = 0; r < 4; ++r) {
          float v = acc[m][n][r] + bv;
          if (OUT_BF16) ((u16*)Cout)[(row + r) * (long)N + col] = f2bf(v);
          else          ((float*)Cout)[(row + r) * (long)N + col] = v;
        }
      }
    }
  }
}

// ---- RoPE in-place on QKV bf16 buffer (q heads 0..63, k heads 64..71) ----
__global__ __launch_bounds__(256) void rope_kernel(u16* __restrict__ QKV,
                                                   const float* __restrict__ cosb,
                                                   const float* __restrict__ sinb) {
  long idx = (long)blockIdx.x * 256 + threadIdx.x;
  if (idx >= (long)SEQ * 72 * 32) return;
  int d = idx & 31;
  int h = (int)((idx >> 5) % 72);
  int s = (int)(idx / (72 * 32));
  int col = (h < 64) ? h * 64 : 4096 + (h - 64) * 64;
  u16* p = QKV + (long)s * NQKV + col;
  float x1 = bf2f(p[d]), x2 = bf2f(p[d + 32]);
  float c = cosb[s * 64 + d], sn = sinb[s * 64 + d];
  p[d]      = f2bf(x1 * c - x2 * sn);
  p[d + 32] = f2bf(x2 * c + x1 * sn);
}

// ---- sliding-window attention with sinks (unchanged) ----
__global__ __launch_bounds__(256, 1) void attn_kernel(const u16* __restrict__ QKV,
                                                      const float* __restrict__ sinks,
                                                      u16* __restrict__ Oa) {
  __shared__ u16 Ks[64 * 64];
  __shared__ u16 Vt[64 * 64];
  __shared__ u16 Ps[4][64 * 72];
  const int tid = threadIdx.x, wid = tid >> 6, lane = tid & 63;
  const int lr = lane & 15, lk = lane >> 4;
  const int i0 = blockIdx.x * 64;
  const int h = blockIdx.y * 4 + wid;
  const int g = h >> 3;

  bf16x8 qf[4][2];
#pragma unroll
  for (int m = 0; m < 4; ++m)
#pragma unroll
    for (int kc = 0; kc < 2; ++kc)
      qf[m][kc] = *(const bf16x8*)&QKV[(long)(i0 + m * 16 + lr) * NQKV + h * 64 + kc * 32 + lk * 8];

  const float sinkh = sinks[h];
  float mrun[4][4], lrun[4][4];
  f32x4 oacc[4][4] = {};
#pragma unroll
  for (int m = 0; m < 4; ++m)
#pragma unroll
    for (int r = 0; r < 4; ++r) { mrun[m][r] = sinkh; lrun[m][r] = 0.f; }

  const int jb0 = (i0 >= 128) ? (i0 - 128) : 0;
  for (int jb = jb0; jb <= i0; jb += 64) {
#pragma unroll
    for (int i = 0; i < 2; ++i) {
      int c = wid * 128 + i * 64 + lane;
      int row = c >> 3, sp = c & 7;
      int ssrc = sp ^ (row & 7);
      async_load16(QKV + (long)(jb + row) * NQKV + 4096 + g * 64 + ssrc * 8,
                   ((char*)Ks) + c * 16);
    }
    {
      int j0 = (tid & 31) * 2, d0 = (tid >> 5) * 8;
      const u16* vp = QKV + (long)(jb + j0) * NQKV + 4608 + g * 64 + d0;
      int4 rv0 = *(const int4*)vp;
      int4 rv1 = *(const int4*)(vp + NQKV);
      const u16* a0 = (const u16*)&rv0;
      const u16* a1 = (const u16*)&rv1;
#pragma unroll
      for (int e = 0; e < 8; ++e) {
        int d = d0 + e;
        unsigned val = (unsigned)a0[e] | ((unsigned)a1[e] << 16);
        int byt = d * 128 + ((((j0 >> 3) ^ (d & 7)) << 4)) + ((j0 & 7) * 2);
        *(unsigned*)((char*)Vt + byt) = val;
      }
    }
    __syncthreads();

    f32x4 sf[4][4] = {};
    __builtin_amdgcn_s_setprio(1);
#pragma unroll
    for (int kc = 0; kc < 2; ++kc) {
      bf16x8 kf[4];
#pragma unroll
      for (int cf = 0; cf < 4; ++cf) {
        int row = cf * 16 + lr;
        kf[cf] = *(const bf16x8*)((const char*)Ks + row * 128 + (((kc * 4 + lk) ^ (lr & 7)) << 4));
      }
#pragma unroll
      for (int m = 0; m < 4; ++m)
#pragma unroll
        for (int cf = 0; cf < 4; ++cf)
          sf[m][cf] = __builtin_amdgcn_mfma_f32_16x16x32_bf16(qf[m][kc], kf[cf], sf[m][cf], 0, 0, 0);
    }
    __builtin_amdgcn_s_setprio(0);

#pragma unroll
    for (int m = 0; m < 4; ++m) {
      float rmax[4];
#pragma unroll
      for (int r = 0; r < 4; ++r) {
        int i = i0 + m * 16 + lk * 4 + r;
        float mx = NEG_INF;
#pragma unroll
        for (int cf = 0; cf < 4; ++cf) {
          int j = jb + cf * 16 + lr;
          float v = sf[m][cf][r] * SCALE;
          bool ok = (j <= i) && (j > i - 128);
          v = ok ? v : NEG_INF;
          sf[m][cf][r] = v;
          mx = fmaxf(mx, v);
        }
#pragma unroll
        for (int off = 1; off < 16; off <<= 1) mx = fmaxf(mx, __shfl_xor(mx, off, 64));
        rmax[r] = mx;
      }
#pragma unroll
      for (int r = 0; r < 4; ++r) {
        float mnew = fmaxf(mrun[m][r], rmax[r]);
        float corr = __expf(mrun[m][r] - mnew);
        mrun[m][r] = mnew;
        float rsum = 0.f;
#pragma unroll
        for (int cf = 0; cf < 4; ++cf) {
          float p = __expf(sf[m][cf][r] - mnew);
          sf[m][cf][r] = p;
          rsum += p;
        }
#pragma unroll
        for (int off = 1; off < 16; off <<= 1) rsum += __shfl_xor(rsum, off, 64);
        lrun[m][r] = lrun[m][r] * corr + rsum;
#pragma unroll
        for (int dn = 0; dn < 4; ++dn) oacc[m][dn][r] *= corr;
      }
    }

#pragma unroll
    for (int m = 0; m < 4; ++m)
#pragma unroll
      for (int cf = 0; cf < 4; ++cf)
#pragma unroll
        for (int r = 0; r < 4; ++r)
          Ps[wid][(m * 16 + lk * 4 + r) * 72 + cf * 16 + lr] = f2bf(sf[m][cf][r]);
    __syncthreads();

    __builtin_amdgcn_s_setprio(1);
#pragma unroll
    for (int kc = 0; kc < 2; ++kc) {
      bf16x8 pf[4], vf[4];
#pragma unroll
      for (int m = 0; m < 4; ++m)
        pf[m] = *(const bf16x8*)&Ps[wid][(m * 16 + lr) * 72 + kc * 32 + lk * 8];
#pragma unroll
      for (int dn = 0; dn < 4; ++dn) {
        int row = dn * 16 + lr;
        vf[dn] = *(const bf16x8*)((const char*)Vt + row * 128 + (((kc * 4 + lk) ^ (lr & 7)) << 4));
      }
#pragma unroll
      for (int m = 0; m < 4; ++m)
#pragma unroll
        for (int dn = 0; dn < 4; ++dn)
          oacc[m][dn] = __builtin_amdgcn_mfma_f32_16x16x32_bf16(pf[m], vf[dn], oacc[m][dn], 0, 0, 0);
    }
    __builtin_amdgcn_s_setprio(0);
    __syncthreads();
  }

#pragma unroll
  for (int m = 0; m < 4; ++m)
#pragma unroll
    for (int r = 0; r < 4; ++r) {
      float denom = lrun[m][r] + __expf(sinkh - mrun[m][r]);
      float inv = 1.f / denom;
      long row = i0 + m * 16 + lk * 4 + r;
#pragma unroll
      for (int dn = 0; dn < 4; ++dn)
        Oa[row * 4096 + h * 64 + dn * 16 + lr] = f2bf(oacc[m][dn][r] * inv);
    }
}

extern "C" void kernel_launch(void* const* d_in, const int* in_sizes, int n_in,
                              void* d_out, int out_size, void* d_ws, size_t ws_size,
                              hipStream_t stream) {
  const float* X    = (const float*)d_in[0];
  const float* cosb = (const float*)d_in[1];
  const float* sinb = (const float*)d_in[2];
  const float* Wq   = (const float*)d_in[3];
  const float* bq   = (const float*)d_in[4];
  const float* Wk   = (const float*)d_in[5];
  const float* bk   = (const float*)d_in[6];
  const float* Wv   = (const float*)d_in[7];
  const float* bv   = (const float*)d_in[8];
  const float* Wo   = (const float*)d_in[9];
  const float* bo   = (const float*)d_in[10];
  const float* sinks = (const float*)d_in[11];

  char* ws = (char*)d_ws;
  size_t off = 0;
  auto alloc = [&](size_t bytes) -> void* {
    void* p = ws + off;
    off += (bytes + 255) & ~(size_t)255;
    return p;
  };
  u16*   Xb    = (u16*)alloc((size_t)SEQ * HIDN * 2);            // [2048][2880]
  u16*   Wqkv  = (u16*)alloc((size_t)NQKV * HIDN * 2);           // [5120][2880]
  u16*   Wot   = (u16*)alloc((size_t)3072 * 4096 * 2);           // [3072][4096] (pad rows)
  float* bqkv  = (float*)alloc((size_t)NQKV * 4);
  u16*   QKV   = (u16*)alloc((size_t)SEQ * NQKV * 2);            // [2048][5120]
  u16*   Ab    = (u16*)alloc((size_t)SEQ * 4096 * 2);            // attn out [2048][4096]
  (void)ws_size; (void)in_sizes; (void)n_in; (void)out_size;

  conv_f2b<<<(SEQ * HIDN / 4 + 255) / 256, 256, 0, stream>>>(X, Xb, (long)SEQ * HIDN / 4);
  transpose_f2b<<<dim3(4096 / 32, HIDN / 32), 256, 0, stream>>>(Wq, Wqkv, HIDN, 4096, HIDN);
  transpose_f2b<<<dim3(512 / 32, HIDN / 32), 256, 0, stream>>>(Wk, Wqkv + (size_t)4096 * HIDN, HIDN, 512, HIDN);
  transpose_f2b<<<dim3(512 / 32, HIDN / 32), 256, 0, stream>>>(Wv, Wqkv + (size_t)4608 * HIDN, HIDN, 512, HIDN);
  transpose_f2b<<<dim3(HIDN / 32, 4096 / 32), 256, 0, stream>>>(Wo, Wot, 4096, HIDN, 4096);
  concat_bias<<<(NQKV + 255) / 256, 256, 0, stream>>>(bq, bk, bv, bqkv);
  // QKV projection: [2048][2880] @ [5120][2880]^T -> bf16 [2048][5120]
  gemm_kb<true><<<dim3(SEQ / 128, NQKV / 256), 256, 0, stream>>>(Xb, Wqkv, bqkv, QKV, NQKV, HIDN);
  rope_kernel<<<(int)(((long)SEQ * 72 * 32 + 255) / 256), 256, 0, stream>>>(QKV, cosb, sinb);
  attn_kernel<<<dim3(SEQ / 64, 64 / 4), 256, 0, stream>>>(QKV, sinks, Ab);
  // O-proj: [2048][4096] @ [3072pad][4096]^T -> fp32 [2048][2880]
  gemm_kb<false><<<dim3(SEQ / 128, 3072 / 256), 256, 0, stream>>>(Ab, Wot, bo, (float*)d_out, HIDN, 4096);
}

// Round 5
// 253.096 us; speedup vs baseline: 1.0378x; 1.0378x over previous
//
#include <hip/hip_runtime.h>

typedef unsigned short u16;
typedef __bf16 bf16x8 __attribute__((ext_vector_type(8)));
typedef float f32x4 __attribute__((ext_vector_type(4)));

// ---- problem constants ----
constexpr int SEQ = 2048;
constexpr int HIDN = 2880;
constexpr int NQKV = 5120;   // 4096 q | 512 k | 512 v
constexpr float SCALE = 0.125f;   // 1/sqrt(64)
constexpr float NEG_INF = -1e30f;

#define ASM_VMCNT(n)  asm volatile("s_waitcnt vmcnt(" #n ")" ::: "memory")
#define ASM_LGKM(n)   asm volatile("s_waitcnt lgkmcnt(" #n ")" ::: "memory")
#define ASM_BARRIER() asm volatile("s_barrier" ::: "memory")
#define SCHEDBAR()    __builtin_amdgcn_sched_barrier(0)

__device__ __forceinline__ u16 f2bf(float f) {
  unsigned int u = __builtin_bit_cast(unsigned int, f);
  u += 0x7FFFu + ((u >> 16) & 1u);
  return (u16)(u >> 16);
}
__device__ __forceinline__ float bf2f(u16 h) {
  unsigned int u = ((unsigned int)h) << 16;
  return __builtin_bit_cast(float, u);
}
__device__ __forceinline__ void async_load16(const void* g, void* l) {
  __builtin_amdgcn_global_load_lds(
      (const __attribute__((address_space(1))) unsigned int*)g,
      (__attribute__((address_space(3))) unsigned int*)l, 16, 0, 0);
}
// asm ds_read_b128: opaque to compiler mem-dep tracking; ordering enforced
// by the volatile waitcnt fences + sched_barrier (rule #18).
__device__ __forceinline__ f32x4 DSR(unsigned addr) {
  f32x4 d;
  asm volatile("ds_read_b128 %0, %1" : "=v"(d) : "v"(addr));
  return d;
}
__device__ __forceinline__ bf16x8 asbf(f32x4 v) { return __builtin_bit_cast(bf16x8, v); }

// ---- fp32 -> bf16 flat convert ----
__global__ __launch_bounds__(256) void conv_f2b(const float* __restrict__ in,
                                                u16* __restrict__ out, long n4) {
  long i = (long)blockIdx.x * 256 + threadIdx.x;
  if (i >= n4) return;
  float4 v = ((const float4*)in)[i];
  u16 o0 = f2bf(v.x), o1 = f2bf(v.y), o2 = f2bf(v.z), o3 = f2bf(v.w);
  out[i * 4 + 0] = o0; out[i * 4 + 1] = o1; out[i * 4 + 2] = o2; out[i * 4 + 3] = o3;
}

// ---- fp32 [R][C] -> bf16 out[c][r] (transpose-convert), dims % 32 == 0 ----
__global__ __launch_bounds__(256) void transpose_f2b(const float* __restrict__ in,
                                                     u16* __restrict__ out,
                                                     int R, int C, int ostride) {
  __shared__ float tile[32][33];
  int c0 = blockIdx.x * 32, r0 = blockIdx.y * 32;
  int tx = threadIdx.x & 31, ty = threadIdx.x >> 5;
#pragma unroll
  for (int i = 0; i < 32; i += 8)
    tile[ty + i][tx] = in[(long)(r0 + ty + i) * C + c0 + tx];
  __syncthreads();
#pragma unroll
  for (int i = 0; i < 32; i += 8)
    out[(long)(c0 + ty + i) * ostride + r0 + tx] = f2bf(tile[tx][ty + i]);
}

__global__ __launch_bounds__(256) void concat_bias(const float* bq, const float* bk,
                                                   const float* bv, float* out) {
  int t = blockIdx.x * 256 + threadIdx.x;
  if (t < 4096) out[t] = bq[t];
  else if (t < 4608) out[t] = bk[t - 4096];
  else if (t < 5120) out[t] = bv[t - 4608];
}

// ======== unified GEMM: C[M][N] = A[M][K] @ B_t[N][K]^T + bias ========
// BM=128, BN=256, BK=32; 512 thr = 8 waves (2M x 4N), per-wave 64x64
// (acc = 64 VGPR -> 4 waves/SIMD -> 2 blocks/CU co-resident).
// Double-buffered 24KB tiles (48KB); 3 loads/thread/tile; stage(t+1) into
// buf^1; single vmcnt(3)/tile; T2 slot-XOR swizzle (source-side, verified
// 0-conflict in R4); T1 XCD swizzle; T5 setprio.
template <bool OUT_BF16>
__global__ __launch_bounds__(512, 4) void gemm_w8(const u16* __restrict__ A,
                                                  const u16* __restrict__ B,
                                                  const float* __restrict__ bias,
                                                  void* __restrict__ Cout,
                                                  int N, int K) {
  __shared__ u16 lds[2 * 12288];  // per buf: A[128][32] 8KB | B[256][32] 16KB
  const int tid = threadIdx.x, lane = tid & 63, wid = tid >> 6;
  const int wm = wid >> 2, wn = wid & 3;
  const int lr = lane & 15, lk = lane >> 4;

  // T1: bijective XCD swizzle
  const int gm = gridDim.x;
  int nwg = gm * gridDim.y;
  int bid = blockIdx.y * gm + blockIdx.x;
  int q8 = nwg >> 3, r8 = nwg & 7;
  int xcd = bid & 7, seq = bid >> 3;
  int swz = (xcd < r8 ? xcd * (q8 + 1) : r8 * (q8 + 1) + (xcd - r8) * q8) + seq;
  const long brow = (long)(swz % gm) * 128;
  const long bcol = (long)(swz / gm) * 256;
  const int nkt = K >> 5;

  // staging sources, pre-swizzled: chunk c -> row c>>2, phys slot c&3,
  // logical k-slot = (c&3) ^ ((row>>1)&3) = (c&3) ^ ((c>>3)&3)
  const int c1 = tid + 512;
  const u16* As0 = A + (brow + (tid >> 2)) * (long)K + ((tid & 3) ^ ((tid >> 3) & 3)) * 8;
  const u16* Bs0 = B + (bcol + (tid >> 2)) * (long)K + ((tid & 3) ^ ((tid >> 3) & 3)) * 8;
  const u16* Bs1 = B + (bcol + (c1 >> 2)) * (long)K + ((c1 & 3) ^ ((c1 >> 3) & 3)) * 8;
  char* L = (char*)lds;
  auto stage = [&](int kt, int b) {
    long ko = (long)kt * 32;
    char* d = L + b * 24576;
    async_load16(As0 + ko, d + tid * 16);
    async_load16(Bs0 + ko, d + 8192 + tid * 16);
    async_load16(Bs1 + ko, d + 8192 + c1 * 16);
  };

  // read offsets: row*64 + (lk ^ ((lr>>1)&3))*16  (verified 0-conflict)
  const unsigned lds0 = (unsigned)(size_t)L;
  const unsigned xs = (unsigned)((lk ^ ((lr >> 1) & 3)) << 4);
  const unsigned aoff = lds0 + (unsigned)((wm * 64 + lr) * 64) + xs;           // + m*1024
  const unsigned boff = lds0 + 8192u + (unsigned)((wn * 64 + lr) * 64) + xs;   // + n*1024

  f32x4 acc[4][4] = {};
  stage(0, 0);

  for (int t = 0; t < nkt; ++t) {
    const int b = t & 1;
    // prefetch next tile into the other buffer (read at t-1, drained by the
    // t-1 end barrier); vmcnt(3) guarantees stage(t) landed chip-wide.
    if (t + 1 < nkt) { stage(t + 1, b ^ 1); ASM_VMCNT(3); }
    else             { ASM_VMCNT(0); }
    ASM_BARRIER();

    const unsigned ab = aoff + (unsigned)(b * 24576);
    const unsigned bb = boff + (unsigned)(b * 24576);
    f32x4 af[4], bf4[4];
#pragma unroll
    for (int m = 0; m < 4; ++m) af[m] = DSR(ab + m * 1024u);
#pragma unroll
    for (int n = 0; n < 4; ++n) bf4[n] = DSR(bb + n * 1024u);
    ASM_LGKM(0); SCHEDBAR();
    __builtin_amdgcn_s_setprio(1);
#pragma unroll
    for (int m = 0; m < 4; ++m)
#pragma unroll
      for (int n = 0; n < 4; ++n)
        acc[m][n] = __builtin_amdgcn_mfma_f32_16x16x32_bf16(asbf(af[m]), asbf(bf4[n]), acc[m][n], 0, 0, 0);
    __builtin_amdgcn_s_setprio(0);
    ASM_BARRIER();   // phase-lock + closes WAR window for next stage
  }

#pragma unroll
  for (int m = 0; m < 4; ++m) {
    long row = brow + wm * 64 + m * 16 + lk * 4;
#pragma unroll
    for (int n = 0; n < 4; ++n) {
      long col = bcol + wn * 64 + n * 16 + lr;
      if (col < N) {
        float bv = bias[col];
#pragma unroll
        for (int r = 0; r < 4; ++r) {
          float v = acc[m][n][r] + bv;
          if (OUT_BF16) ((u16*)Cout)[(row + r) * (long)N + col] = f2bf(v);
          else          ((float*)Cout)[(row + r) * (long)N + col] = v;
        }
      }
    }
  }
}

// ---- RoPE in-place on QKV bf16 buffer (q heads 0..63, k heads 64..71) ----
__global__ __launch_bounds__(256) void rope_kernel(u16* __restrict__ QKV,
                                                   const float* __restrict__ cosb,
                                                   const float* __restrict__ sinb) {
  long idx = (long)blockIdx.x * 256 + threadIdx.x;
  if (idx >= (long)SEQ * 72 * 32) return;
  int d = idx & 31;
  int h = (int)((idx >> 5) % 72);
  int s = (int)(idx / (72 * 32));
  int col = (h < 64) ? h * 64 : 4096 + (h - 64) * 64;
  u16* p = QKV + (long)s * NQKV + col;
  float x1 = bf2f(p[d]), x2 = bf2f(p[d + 32]);
  float c = cosb[s * 64 + d], sn = sinb[s * 64 + d];
  p[d]      = f2bf(x1 * c - x2 * sn);
  p[d + 32] = f2bf(x2 * c + x1 * sn);
}

// ---- sliding-window attention with sinks (unchanged) ----
__global__ __launch_bounds__(256, 1) void attn_kernel(const u16* __restrict__ QKV,
                                                      const float* __restrict__ sinks,
                                                      u16* __restrict__ Oa) {
  __shared__ u16 Ks[64 * 64];
  __shared__ u16 Vt[64 * 64];
  __shared__ u16 Ps[4][64 * 72];
  const int tid = threadIdx.x, wid = tid >> 6, lane = tid & 63;
  const int lr = lane & 15, lk = lane >> 4;
  const int i0 = blockIdx.x * 64;
  const int h = blockIdx.y * 4 + wid;
  const int g = h >> 3;

  bf16x8 qf[4][2];
#pragma unroll
  for (int m = 0; m < 4; ++m)
#pragma unroll
    for (int kc = 0; kc < 2; ++kc)
      qf[m][kc] = *(const bf16x8*)&QKV[(long)(i0 + m * 16 + lr) * NQKV + h * 64 + kc * 32 + lk * 8];

  const float sinkh = sinks[h];
  float mrun[4][4], lrun[4][4];
  f32x4 oacc[4][4] = {};
#pragma unroll
  for (int m = 0; m < 4; ++m)
#pragma unroll
    for (int r = 0; r < 4; ++r) { mrun[m][r] = sinkh; lrun[m][r] = 0.f; }

  const int jb0 = (i0 >= 128) ? (i0 - 128) : 0;
  for (int jb = jb0; jb <= i0; jb += 64) {
#pragma unroll
    for (int i = 0; i < 2; ++i) {
      int c = wid * 128 + i * 64 + lane;
      int row = c >> 3, sp = c & 7;
      int ssrc = sp ^ (row & 7);
      async_load16(QKV + (long)(jb + row) * NQKV + 4096 + g * 64 + ssrc * 8,
                   ((char*)Ks) + c * 16);
    }
    {
      int j0 = (tid & 31) * 2, d0 = (tid >> 5) * 8;
      const u16* vp = QKV + (long)(jb + j0) * NQKV + 4608 + g * 64 + d0;
      int4 rv0 = *(const int4*)vp;
      int4 rv1 = *(const int4*)(vp + NQKV);
      const u16* a0 = (const u16*)&rv0;
      const u16* a1 = (const u16*)&rv1;
#pragma unroll
      for (int e = 0; e < 8; ++e) {
        int d = d0 + e;
        unsigned val = (unsigned)a0[e] | ((unsigned)a1[e] << 16);
        int byt = d * 128 + ((((j0 >> 3) ^ (d & 7)) << 4)) + ((j0 & 7) * 2);
        *(unsigned*)((char*)Vt + byt) = val;
      }
    }
    __syncthreads();

    f32x4 sf[4][4] = {};
    __builtin_amdgcn_s_setprio(1);
#pragma unroll
    for (int kc = 0; kc < 2; ++kc) {
      bf16x8 kf[4];
#pragma unroll
      for (int cf = 0; cf < 4; ++cf) {
        int row = cf * 16 + lr;
        kf[cf] = *(const bf16x8*)((const char*)Ks + row * 128 + (((kc * 4 + lk) ^ (lr & 7)) << 4));
      }
#pragma unroll
      for (int m = 0; m < 4; ++m)
#pragma unroll
        for (int cf = 0; cf < 4; ++cf)
          sf[m][cf] = __builtin_amdgcn_mfma_f32_16x16x32_bf16(qf[m][kc], kf[cf], sf[m][cf], 0, 0, 0);
    }
    __builtin_amdgcn_s_setprio(0);

#pragma unroll
    for (int m = 0; m < 4; ++m) {
      float rmax[4];
#pragma unroll
      for (int r = 0; r < 4; ++r) {
        int i = i0 + m * 16 + lk * 4 + r;
        float mx = NEG_INF;
#pragma unroll
        for (int cf = 0; cf < 4; ++cf) {
          int j = jb + cf * 16 + lr;
          float v = sf[m][cf][r] * SCALE;
          bool ok = (j <= i) && (j > i - 128);
          v = ok ? v : NEG_INF;
          sf[m][cf][r] = v;
          mx = fmaxf(mx, v);
        }
#pragma unroll
        for (int off = 1; off < 16; off <<= 1) mx = fmaxf(mx, __shfl_xor(mx, off, 64));
        rmax[r] = mx;
      }
#pragma unroll
      for (int r = 0; r < 4; ++r) {
        float mnew = fmaxf(mrun[m][r], rmax[r]);
        float corr = __expf(mrun[m][r] - mnew);
        mrun[m][r] = mnew;
        float rsum = 0.f;
#pragma unroll
        for (int cf = 0; cf < 4; ++cf) {
          float p = __expf(sf[m][cf][r] - mnew);
          sf[m][cf][r] = p;
          rsum += p;
        }
#pragma unroll
        for (int off = 1; off < 16; off <<= 1) rsum += __shfl_xor(rsum, off, 64);
        lrun[m][r] = lrun[m][r] * corr + rsum;
#pragma unroll
        for (int dn = 0; dn < 4; ++dn) oacc[m][dn][r] *= corr;
      }
    }

#pragma unroll
    for (int m = 0; m < 4; ++m)
#pragma unroll
      for (int cf = 0; cf < 4; ++cf)
#pragma unroll
        for (int r = 0; r < 4; ++r)
          Ps[wid][(m * 16 + lk * 4 + r) * 72 + cf * 16 + lr] = f2bf(sf[m][cf][r]);
    __syncthreads();

    __builtin_amdgcn_s_setprio(1);
#pragma unroll
    for (int kc = 0; kc < 2; ++kc) {
      bf16x8 pf[4], vf[4];
#pragma unroll
      for (int m = 0; m < 4; ++m)
        pf[m] = *(const bf16x8*)&Ps[wid][(m * 16 + lr) * 72 + kc * 32 + lk * 8];
#pragma unroll
      for (int dn = 0; dn < 4; ++dn) {
        int row = dn * 16 + lr;
        vf[dn] = *(const bf16x8*)((const char*)Vt + row * 128 + (((kc * 4 + lk) ^ (lr & 7)) << 4));
      }
#pragma unroll
      for (int m = 0; m < 4; ++m)
#pragma unroll
        for (int dn = 0; dn < 4; ++dn)
          oacc[m][dn] = __builtin_amdgcn_mfma_f32_16x16x32_bf16(pf[m], vf[dn], oacc[m][dn], 0, 0, 0);
    }
    __builtin_amdgcn_s_setprio(0);
    __syncthreads();
  }

#pragma unroll
  for (int m = 0; m < 4; ++m)
#pragma unroll
    for (int r = 0; r < 4; ++r) {
      float denom = lrun[m][r] + __expf(sinkh - mrun[m][r]);
      float inv = 1.f / denom;
      long row = i0 + m * 16 + lk * 4 + r;
#pragma unroll
      for (int dn = 0; dn < 4; ++dn)
        Oa[row * 4096 + h * 64 + dn * 16 + lr] = f2bf(oacc[m][dn][r] * inv);
    }
}

extern "C" void kernel_launch(void* const* d_in, const int* in_sizes, int n_in,
                              void* d_out, int out_size, void* d_ws, size_t ws_size,
                              hipStream_t stream) {
  const float* X    = (const float*)d_in[0];
  const float* cosb = (const float*)d_in[1];
  const float* sinb = (const float*)d_in[2];
  const float* Wq   = (const float*)d_in[3];
  const float* bq   = (const float*)d_in[4];
  const float* Wk   = (const float*)d_in[5];
  const float* bk   = (const float*)d_in[6];
  const float* Wv   = (const float*)d_in[7];
  const float* bv   = (const float*)d_in[8];
  const float* Wo   = (const float*)d_in[9];
  const float* bo   = (const float*)d_in[10];
  const float* sinks = (const float*)d_in[11];

  char* ws = (char*)d_ws;
  size_t off = 0;
  auto alloc = [&](size_t bytes) -> void* {
    void* p = ws + off;
    off += (bytes + 255) & ~(size_t)255;
    return p;
  };
  u16*   Xb    = (u16*)alloc((size_t)SEQ * HIDN * 2);            // [2048][2880]
  u16*   Wqkv  = (u16*)alloc((size_t)NQKV * HIDN * 2);           // [5120][2880]
  u16*   Wot   = (u16*)alloc((size_t)3072 * 4096 * 2);           // [3072][4096] (pad rows)
  float* bqkv  = (float*)alloc((size_t)NQKV * 4);
  u16*   QKV   = (u16*)alloc((size_t)SEQ * NQKV * 2);            // [2048][5120]
  u16*   Ab    = (u16*)alloc((size_t)SEQ * 4096 * 2);            // attn out [2048][4096]
  (void)ws_size; (void)in_sizes; (void)n_in; (void)out_size;

  conv_f2b<<<(SEQ * HIDN / 4 + 255) / 256, 256, 0, stream>>>(X, Xb, (long)SEQ * HIDN / 4);
  transpose_f2b<<<dim3(4096 / 32, HIDN / 32), 256, 0, stream>>>(Wq, Wqkv, HIDN, 4096, HIDN);
  transpose_f2b<<<dim3(512 / 32, HIDN / 32), 256, 0, stream>>>(Wk, Wqkv + (size_t)4096 * HIDN, HIDN, 512, HIDN);
  transpose_f2b<<<dim3(512 / 32, HIDN / 32), 256, 0, stream>>>(Wv, Wqkv + (size_t)4608 * HIDN, HIDN, 512, HIDN);
  transpose_f2b<<<dim3(HIDN / 32, 4096 / 32), 256, 0, stream>>>(Wo, Wot, 4096, HIDN, 4096);
  concat_bias<<<(NQKV + 255) / 256, 256, 0, stream>>>(bq, bk, bv, bqkv);
  // QKV projection: [2048][2880] @ [5120][2880]^T -> bf16 [2048][5120]
  gemm_w8<true><<<dim3(SEQ / 128, NQKV / 256), 512, 0, stream>>>(Xb, Wqkv, bqkv, QKV, NQKV, HIDN);
  rope_kernel<<<(int)(((long)SEQ * 72 * 32 + 255) / 256), 256, 0, stream>>>(QKV, cosb, sinb);
  attn_kernel<<<dim3(SEQ / 64, 64 / 4), 256, 0, stream>>>(QKV, sinks, Ab);
  // O-proj: [2048][4096] @ [3072pad][4096]^T -> fp32 [2048][2880]
  gemm_w8<false><<<dim3(SEQ / 128, 3072 / 256), 512, 0, stream>>>(Ab, Wot, bo, (float*)d_out, HIDN, 4096);
}

// Round 6
// 251.840 us; speedup vs baseline: 1.0429x; 1.0050x over previous
//
#include <hip/hip_runtime.h>

typedef unsigned short u16;
typedef __bf16 bf16x8 __attribute__((ext_vector_type(8)));
typedef float f32x4 __attribute__((ext_vector_type(4)));

// ---- problem constants ----
constexpr int SEQ = 2048;
constexpr int HIDN = 2880;
constexpr int NQKV = 5120;   // 4096 q | 512 k | 512 v
constexpr float SCALE = 0.125f;   // 1/sqrt(64)
constexpr float NEG_INF = -1e30f;

#define ASM_VMCNT(n)  asm volatile("s_waitcnt vmcnt(" #n ")" ::: "memory")
#define ASM_LGKM(n)   asm volatile("s_waitcnt lgkmcnt(" #n ")" ::: "memory")
#define ASM_BARRIER() asm volatile("s_barrier" ::: "memory")
#define SCHEDBAR()    __builtin_amdgcn_sched_barrier(0)

__device__ __forceinline__ u16 f2bf(float f) {
  unsigned int u = __builtin_bit_cast(unsigned int, f);
  u += 0x7FFFu + ((u >> 16) & 1u);
  return (u16)(u >> 16);
}
__device__ __forceinline__ float bf2f(u16 h) {
  unsigned int u = ((unsigned int)h) << 16;
  return __builtin_bit_cast(float, u);
}
__device__ __forceinline__ void async_load16(const void* g, void* l) {
  __builtin_amdgcn_global_load_lds(
      (const __attribute__((address_space(1))) unsigned int*)g,
      (__attribute__((address_space(3))) unsigned int*)l, 16, 0, 0);
}
// asm ds_read_b128: opaque to compiler mem-dep tracking; ordering enforced
// by the volatile waitcnt fences + sched_barrier (rule #18).
__device__ __forceinline__ f32x4 DSR(unsigned addr) {
  f32x4 d;
  asm volatile("ds_read_b128 %0, %1" : "=v"(d) : "v"(addr));
  return d;
}
__device__ __forceinline__ bf16x8 asbf(f32x4 v) { return __builtin_bit_cast(bf16x8, v); }

// ---- fp32 -> bf16 flat convert ----
__global__ __launch_bounds__(256) void conv_f2b(const float* __restrict__ in,
                                                u16* __restrict__ out, long n4) {
  long i = (long)blockIdx.x * 256 + threadIdx.x;
  if (i >= n4) return;
  float4 v = ((const float4*)in)[i];
  u16 o0 = f2bf(v.x), o1 = f2bf(v.y), o2 = f2bf(v.z), o3 = f2bf(v.w);
  out[i * 4 + 0] = o0; out[i * 4 + 1] = o1; out[i * 4 + 2] = o2; out[i * 4 + 3] = o3;
}

// ---- fp32 [R][C] -> bf16 out[c][r] (transpose-convert), dims % 32 == 0 ----
__global__ __launch_bounds__(256) void transpose_f2b(const float* __restrict__ in,
                                                     u16* __restrict__ out,
                                                     int R, int C, int ostride) {
  __shared__ float tile[32][33];
  int c0 = blockIdx.x * 32, r0 = blockIdx.y * 32;
  int tx = threadIdx.x & 31, ty = threadIdx.x >> 5;
#pragma unroll
  for (int i = 0; i < 32; i += 8)
    tile[ty + i][tx] = in[(long)(r0 + ty + i) * C + c0 + tx];
  __syncthreads();
#pragma unroll
  for (int i = 0; i < 32; i += 8)
    out[(long)(c0 + ty + i) * ostride + r0 + tx] = f2bf(tile[tx][ty + i]);
}

__global__ __launch_bounds__(256) void concat_bias(const float* bq, const float* bk,
                                                   const float* bv, float* out) {
  int t = blockIdx.x * 256 + threadIdx.x;
  if (t < 4096) out[t] = bq[t];
  else if (t < 4608) out[t] = bk[t - 4096];
  else if (t < 5120) out[t] = bv[t - 4608];
}

// ======== 8-phase 256x256 GEMM (m201 template, BK=32) ========
// C[M][N] = A[M][K] @ B_t[N][K]^T (+bias if MODE 0).
// 512 thr = 8 waves (2M x 4N), per-wave 128x64, acc[8][4].
// LDS = 8 half-buffers x 8KB = 64KB: [db][Alo,Ahi,Blo,Bhi], half = [128r][32k].
// Iter = 2 K-tiles (E=db0, O=db1), 8 phases = C-quadrants:
//  P1 rdA(E,lo)+rdB(E,lo)+stage Alo(O)   -> q(0,0)
//  P2 rdB(E,hi)+stage Ahi(O)             -> q(0,1)
//  P3 rdA(E,hi)+stage Blo(E+2)           -> q(1,1)
//  P4 stage Bhi(E+2) + VMCNT(2)          -> q(1,0)
//  P5..P8 same on O, staging Alo/Ahi(E+2), Blo/Bhi(O+2), VMCNT(2) at P8.
// vmcnt ledger: at P4, outstanding<=P3,P4 => A(O)[P1,P2] + B(O)[prev P7,P8]
// landed. At P8, outstanding<=P7,P8 => A/B(E+2)[P3..P6] landed for next P1.
// WAR: each stage targets a half whose last reader finished a barrier ago.
// MODE 1: z-split-K (blockIdx.z), fp32 partials, no bias.
template <int MODE>
__global__ __launch_bounds__(512, 2) void gemm8p(const u16* __restrict__ A,
                                                 const u16* __restrict__ Bp,
                                                 const float* __restrict__ bias,
                                                 void* __restrict__ out0,
                                                 float* __restrict__ out1,
                                                 int N, int Kst, int nkt) {
  __shared__ u16 lds[32768];  // 64KB
  const int tid = threadIdx.x, lane = tid & 63, wid = tid >> 6;
  const int wm = wid >> 2, wn = wid & 3;
  const int lr = lane & 15, lk = lane >> 4;

  // T1: bijective XCD swizzle over (x,y)
  const int gm = gridDim.x;
  int nwg = gm * gridDim.y;
  int bid = blockIdx.y * gm + blockIdx.x;
  int q8 = nwg >> 3, r8 = nwg & 7;
  int xcd = bid & 7, seq = bid >> 3;
  int swz = (xcd < r8 ? xcd * (q8 + 1) : r8 * (q8 + 1) + (xcd - r8) * q8) + seq;
  const long brow = (long)(swz % gm) * 256;
  const long bcol = (long)(swz / gm) * 256;
  const long kbase = (MODE == 1) ? (long)blockIdx.z * nkt * 32 : 0;

  char* L = (char*)lds;
  // staging: chunk c=tid -> half row r0=tid>>2, phys slot tid&3,
  // source k pre-swizzled (both-sides rule): logical = phys ^ ((row>>1)&3)
  const int r0 = tid >> 2;
  const int srck = ((tid & 3) ^ ((tid >> 3) & 3)) * 8;
  auto stage1 = [&](int kt, int h) {
    const u16* s;
    if (h < 2) s = A  + (brow + h * 128 + r0) * (long)Kst + kbase + (long)kt * 32 + srck;
    else       s = Bp + (bcol + (h - 2) * 128 + r0) * (long)Kst + kbase + (long)kt * 32 + srck;
    async_load16(s, L + ((kt & 1) * 4 + h) * 8192 + tid * 16);
  };

  // reads: phys slot = lk ^ ((lr>>1)&3) (HW-verified 0-conflict family)
  const unsigned lds0 = (unsigned)(size_t)L;
  const unsigned xk = (unsigned)((lk ^ ((lr >> 1) & 3)) << 4);
  const unsigned raB = lds0 + (unsigned)(wm * 8192 + lr * 64) + xk;
  const unsigned rbB = lds0 + 16384u + (unsigned)((wn >> 1) * 8192 + ((wn & 1) * 64 + lr) * 64) + xk;

  f32x4 acc[8][4] = {};
  auto readA4 = [&](int db, int mh, f32x4* d) {
#pragma unroll
    for (int mf = 0; mf < 4; ++mf)
      d[mf] = DSR(raB + (unsigned)(db * 32768 + mh * 4096 + mf * 1024));
  };
  auto readB2 = [&](int db, int nh, f32x4* d) {
#pragma unroll
    for (int nf = 0; nf < 2; ++nf)
      d[nf] = DSR(rbB + (unsigned)(db * 32768 + nh * 2048 + nf * 1024));
  };
  auto quad8 = [&](int mb, int nb, const f32x4* af, const f32x4* bf) {
#pragma unroll
    for (int mf = 0; mf < 4; ++mf)
#pragma unroll
      for (int nf = 0; nf < 2; ++nf)
        acc[mb + mf][nb + nf] = __builtin_amdgcn_mfma_f32_16x16x32_bf16(
            asbf(af[mf]), asbf(bf[nf]), acc[mb + mf][nb + nf], 0, 0, 0);
  };

  // prologue: tile0 all halves + tile1 B halves; vmcnt(2) => tile0 landed
  stage1(0, 0); stage1(0, 1); stage1(0, 2); stage1(0, 3);
  stage1(1, 2); stage1(1, 3);
  ASM_VMCNT(2);
  ASM_BARRIER();

  const int niter = nkt >> 1;
  for (int it = 0; it < niter; ++it) {
    const int E = it * 2;
    const bool sE2 = (E + 2 < nkt), sO2 = (E + 3 < nkt);
    f32x4 a0[4], a1[4], b0[2], b1[2];
    // ---- P1 ----
    readA4(0, 0, a0); readB2(0, 0, b0);
    stage1(E + 1, 0);
    ASM_BARRIER(); ASM_LGKM(0); SCHEDBAR();
    __builtin_amdgcn_s_setprio(1); quad8(0, 0, a0, b0); __builtin_amdgcn_s_setprio(0);
    ASM_BARRIER();
    // ---- P2 ----
    readB2(0, 1, b1);
    stage1(E + 1, 1);
    ASM_BARRIER(); ASM_LGKM(0); SCHEDBAR();
    __builtin_amdgcn_s_setprio(1); quad8(0, 2, a0, b1); __builtin_amdgcn_s_setprio(0);
    ASM_BARRIER();
    // ---- P3 ----
    readA4(0, 1, a1);
    if (sE2) stage1(E + 2, 2);
    ASM_BARRIER(); ASM_LGKM(0); SCHEDBAR();
    __builtin_amdgcn_s_setprio(1); quad8(4, 2, a1, b1); __builtin_amdgcn_s_setprio(0);
    ASM_BARRIER();
    // ---- P4 ----
    if (sE2) { stage1(E + 2, 3); ASM_VMCNT(2); } else { ASM_VMCNT(0); }
    ASM_BARRIER(); SCHEDBAR();
    __builtin_amdgcn_s_setprio(1); quad8(4, 0, a1, b0); __builtin_amdgcn_s_setprio(0);
    ASM_BARRIER();
    // ---- P5 ----
    readA4(1, 0, a0); readB2(1, 0, b0);
    if (sE2) stage1(E + 2, 0);
    ASM_BARRIER(); ASM_LGKM(0); SCHEDBAR();
    __builtin_amdgcn_s_setprio(1); quad8(0, 0, a0, b0); __builtin_amdgcn_s_setprio(0);
    ASM_BARRIER();
    // ---- P6 ----
    readB2(1, 1, b1);
    if (sE2) stage1(E + 2, 1);
    ASM_BARRIER(); ASM_LGKM(0); SCHEDBAR();
    __builtin_amdgcn_s_setprio(1); quad8(0, 2, a0, b1); __builtin_amdgcn_s_setprio(0);
    ASM_BARRIER();
    // ---- P7 ----
    readA4(1, 1, a1);
    if (sO2) stage1(E + 3, 2);
    ASM_BARRIER(); ASM_LGKM(0); SCHEDBAR();
    __builtin_amdgcn_s_setprio(1); quad8(4, 2, a1, b1); __builtin_amdgcn_s_setprio(0);
    ASM_BARRIER();
    // ---- P8 ----
    if (sO2) { stage1(E + 3, 3); ASM_VMCNT(2); } else { ASM_VMCNT(0); }
    ASM_BARRIER(); SCHEDBAR();
    __builtin_amdgcn_s_setprio(1); quad8(4, 0, a1, b0); __builtin_amdgcn_s_setprio(0);
    ASM_BARRIER();
  }

  // epilogue
#pragma unroll
  for (int mf = 0; mf < 8; ++mf) {
    long row = brow + wm * 128 + mf * 16 + lk * 4;
#pragma unroll
    for (int nf = 0; nf < 4; ++nf) {
      long col = bcol + wn * 64 + nf * 16 + lr;
      if (col < N) {
        if (MODE == 0) {
          float bv = bias[col];
#pragma unroll
          for (int r = 0; r < 4; ++r)
            ((u16*)out0)[(row + r) * (long)N + col] = f2bf(acc[mf][nf][r] + bv);
        } else {
          float* o = (blockIdx.z == 0) ? (float*)out0 : out1;
#pragma unroll
          for (int r = 0; r < 4; ++r)
            o[(row + r) * (long)N + col] = acc[mf][nf][r];
        }
      }
    }
  }
}

// ---- combine split-K partials: out = out + P1 + bias ----
__global__ __launch_bounds__(256) void combine_out(const float* __restrict__ P1,
                                                   const float* __restrict__ bias,
                                                   float* __restrict__ out) {
  long i = (long)blockIdx.x * 256 + threadIdx.x;
  if (i >= (long)SEQ * HIDN / 4) return;
  int c4 = (int)(i % (HIDN / 4));
  float4 p0 = ((const float4*)out)[i];
  float4 p1 = ((const float4*)P1)[i];
  float4 b = ((const float4*)bias)[c4];
  float4 r;
  r.x = p0.x + p1.x + b.x; r.y = p0.y + p1.y + b.y;
  r.z = p0.z + p1.z + b.z; r.w = p0.w + p1.w + b.w;
  ((float4*)out)[i] = r;
}

// ---- RoPE in-place on QKV bf16 buffer (q heads 0..63, k heads 64..71) ----
__global__ __launch_bounds__(256) void rope_kernel(u16* __restrict__ QKV,
                                                   const float* __restrict__ cosb,
                                                   const float* __restrict__ sinb) {
  long idx = (long)blockIdx.x * 256 + threadIdx.x;
  if (idx >= (long)SEQ * 72 * 32) return;
  int d = idx & 31;
  int h = (int)((idx >> 5) % 72);
  int s = (int)(idx / (72 * 32));
  int col = (h < 64) ? h * 64 : 4096 + (h - 64) * 64;
  u16* p = QKV + (long)s * NQKV + col;
  float x1 = bf2f(p[d]), x2 = bf2f(p[d + 32]);
  float c = cosb[s * 64 + d], sn = sinb[s * 64 + d];
  p[d]      = f2bf(x1 * c - x2 * sn);
  p[d + 32] = f2bf(x2 * c + x1 * sn);
}

// ---- sliding-window attention with sinks (unchanged) ----
__global__ __launch_bounds__(256, 1) void attn_kernel(const u16* __restrict__ QKV,
                                                      const float* __restrict__ sinks,
                                                      u16* __restrict__ Oa) {
  __shared__ u16 Ks[64 * 64];
  __shared__ u16 Vt[64 * 64];
  __shared__ u16 Ps[4][64 * 72];
  const int tid = threadIdx.x, wid = tid >> 6, lane = tid & 63;
  const int lr = lane & 15, lk = lane >> 4;
  const int i0 = blockIdx.x * 64;
  const int h = blockIdx.y * 4 + wid;
  const int g = h >> 3;

  bf16x8 qf[4][2];
#pragma unroll
  for (int m = 0; m < 4; ++m)
#pragma unroll
    for (int kc = 0; kc < 2; ++kc)
      qf[m][kc] = *(const bf16x8*)&QKV[(long)(i0 + m * 16 + lr) * NQKV + h * 64 + kc * 32 + lk * 8];

  const float sinkh = sinks[h];
  float mrun[4][4], lrun[4][4];
  f32x4 oacc[4][4] = {};
#pragma unroll
  for (int m = 0; m < 4; ++m)
#pragma unroll
    for (int r = 0; r < 4; ++r) { mrun[m][r] = sinkh; lrun[m][r] = 0.f; }

  const int jb0 = (i0 >= 128) ? (i0 - 128) : 0;
  for (int jb = jb0; jb <= i0; jb += 64) {
#pragma unroll
    for (int i = 0; i < 2; ++i) {
      int c = wid * 128 + i * 64 + lane;
      int row = c >> 3, sp = c & 7;
      int ssrc = sp ^ (row & 7);
      async_load16(QKV + (long)(jb + row) * NQKV + 4096 + g * 64 + ssrc * 8,
                   ((char*)Ks) + c * 16);
    }
    {
      int j0 = (tid & 31) * 2, d0 = (tid >> 5) * 8;
      const u16* vp = QKV + (long)(jb + j0) * NQKV + 4608 + g * 64 + d0;
      int4 rv0 = *(const int4*)vp;
      int4 rv1 = *(const int4*)(vp + NQKV);
      const u16* a0 = (const u16*)&rv0;
      const u16* a1 = (const u16*)&rv1;
#pragma unroll
      for (int e = 0; e < 8; ++e) {
        int d = d0 + e;
        unsigned val = (unsigned)a0[e] | ((unsigned)a1[e] << 16);
        int byt = d * 128 + ((((j0 >> 3) ^ (d & 7)) << 4)) + ((j0 & 7) * 2);
        *(unsigned*)((char*)Vt + byt) = val;
      }
    }
    __syncthreads();

    f32x4 sf[4][4] = {};
    __builtin_amdgcn_s_setprio(1);
#pragma unroll
    for (int kc = 0; kc < 2; ++kc) {
      bf16x8 kf[4];
#pragma unroll
      for (int cf = 0; cf < 4; ++cf) {
        int row = cf * 16 + lr;
        kf[cf] = *(const bf16x8*)((const char*)Ks + row * 128 + (((kc * 4 + lk) ^ (lr & 7)) << 4));
      }
#pragma unroll
      for (int m = 0; m < 4; ++m)
#pragma unroll
        for (int cf = 0; cf < 4; ++cf)
          sf[m][cf] = __builtin_amdgcn_mfma_f32_16x16x32_bf16(qf[m][kc], kf[cf], sf[m][cf], 0, 0, 0);
    }
    __builtin_amdgcn_s_setprio(0);

#pragma unroll
    for (int m = 0; m < 4; ++m) {
      float rmax[4];
#pragma unroll
      for (int r = 0; r < 4; ++r) {
        int i = i0 + m * 16 + lk * 4 + r;
        float mx = NEG_INF;
#pragma unroll
        for (int cf = 0; cf < 4; ++cf) {
          int j = jb + cf * 16 + lr;
          float v = sf[m][cf][r] * SCALE;
          bool ok = (j <= i) && (j > i - 128);
          v = ok ? v : NEG_INF;
          sf[m][cf][r] = v;
          mx = fmaxf(mx, v);
        }
#pragma unroll
        for (int off = 1; off < 16; off <<= 1) mx = fmaxf(mx, __shfl_xor(mx, off, 64));
        rmax[r] = mx;
      }
#pragma unroll
      for (int r = 0; r < 4; ++r) {
        float mnew = fmaxf(mrun[m][r], rmax[r]);
        float corr = __expf(mrun[m][r] - mnew);
        mrun[m][r] = mnew;
        float rsum = 0.f;
#pragma unroll
        for (int cf = 0; cf < 4; ++cf) {
          float p = __expf(sf[m][cf][r] - mnew);
          sf[m][cf][r] = p;
          rsum += p;
        }
#pragma unroll
        for (int off = 1; off < 16; off <<= 1) rsum += __shfl_xor(rsum, off, 64);
        lrun[m][r] = lrun[m][r] * corr + rsum;
#pragma unroll
        for (int dn = 0; dn < 4; ++dn) oacc[m][dn][r] *= corr;
      }
    }

#pragma unroll
    for (int m = 0; m < 4; ++m)
#pragma unroll
      for (int cf = 0; cf < 4; ++cf)
#pragma unroll
        for (int r = 0; r < 4; ++r)
          Ps[wid][(m * 16 + lk * 4 + r) * 72 + cf * 16 + lr] = f2bf(sf[m][cf][r]);
    __syncthreads();

    __builtin_amdgcn_s_setprio(1);
#pragma unroll
    for (int kc = 0; kc < 2; ++kc) {
      bf16x8 pf[4], vf[4];
#pragma unroll
      for (int m = 0; m < 4; ++m)
        pf[m] = *(const bf16x8*)&Ps[wid][(m * 16 + lr) * 72 + kc * 32 + lk * 8];
#pragma unroll
      for (int dn = 0; dn < 4; ++dn) {
        int row = dn * 16 + lr;
        vf[dn] = *(const bf16x8*)((const char*)Vt + row * 128 + (((kc * 4 + lk) ^ (lr & 7)) << 4));
      }
#pragma unroll
      for (int m = 0; m < 4; ++m)
#pragma unroll
        for (int dn = 0; dn < 4; ++dn)
          oacc[m][dn] = __builtin_amdgcn_mfma_f32_16x16x32_bf16(pf[m], vf[dn], oacc[m][dn], 0, 0, 0);
    }
    __builtin_amdgcn_s_setprio(0);
    __syncthreads();
  }

#pragma unroll
  for (int m = 0; m < 4; ++m)
#pragma unroll
    for (int r = 0; r < 4; ++r) {
      float denom = lrun[m][r] + __expf(sinkh - mrun[m][r]);
      float inv = 1.f / denom;
      long row = i0 + m * 16 + lk * 4 + r;
#pragma unroll
      for (int dn = 0; dn < 4; ++dn)
        Oa[row * 4096 + h * 64 + dn * 16 + lr] = f2bf(oacc[m][dn][r] * inv);
    }
}

extern "C" void kernel_launch(void* const* d_in, const int* in_sizes, int n_in,
                              void* d_out, int out_size, void* d_ws, size_t ws_size,
                              hipStream_t stream) {
  const float* X    = (const float*)d_in[0];
  const float* cosb = (const float*)d_in[1];
  const float* sinb = (const float*)d_in[2];
  const float* Wq   = (const float*)d_in[3];
  const float* bq   = (const float*)d_in[4];
  const float* Wk   = (const float*)d_in[5];
  const float* bk   = (const float*)d_in[6];
  const float* Wv   = (const float*)d_in[7];
  const float* bv   = (const float*)d_in[8];
  const float* Wo   = (const float*)d_in[9];
  const float* bo   = (const float*)d_in[10];
  const float* sinks = (const float*)d_in[11];

  char* ws = (char*)d_ws;
  size_t off = 0;
  auto alloc = [&](size_t bytes) -> void* {
    void* p = ws + off;
    off += (bytes + 255) & ~(size_t)255;
    return p;
  };
  u16*   Xb    = (u16*)alloc((size_t)SEQ * HIDN * 2);            // [2048][2880]
  u16*   Wqkv  = (u16*)alloc((size_t)NQKV * HIDN * 2);           // [5120][2880]
  u16*   Wot   = (u16*)alloc((size_t)3072 * 4096 * 2);           // [3072][4096] (pad rows)
  float* bqkv  = (float*)alloc((size_t)NQKV * 4);
  u16*   QKV   = (u16*)alloc((size_t)SEQ * NQKV * 2);            // [2048][5120]
  u16*   Ab    = (u16*)alloc((size_t)SEQ * 4096 * 2);            // attn out [2048][4096]
  // split-K partial 1 reuses Wqkv scratch (29.5MB >= 23.6MB; Wqkv dead after QKV GEMM)
  float* Pt1 = (float*)Wqkv;
  (void)ws_size; (void)in_sizes; (void)n_in; (void)out_size;

  conv_f2b<<<(SEQ * HIDN / 4 + 255) / 256, 256, 0, stream>>>(X, Xb, (long)SEQ * HIDN / 4);
  transpose_f2b<<<dim3(4096 / 32, HIDN / 32), 256, 0, stream>>>(Wq, Wqkv, HIDN, 4096, HIDN);
  transpose_f2b<<<dim3(512 / 32, HIDN / 32), 256, 0, stream>>>(Wk, Wqkv + (size_t)4096 * HIDN, HIDN, 512, HIDN);
  transpose_f2b<<<dim3(512 / 32, HIDN / 32), 256, 0, stream>>>(Wv, Wqkv + (size_t)4608 * HIDN, HIDN, 512, HIDN);
  transpose_f2b<<<dim3(HIDN / 32, 4096 / 32), 256, 0, stream>>>(Wo, Wot, 4096, HIDN, 4096);
  concat_bias<<<(NQKV + 255) / 256, 256, 0, stream>>>(bq, bk, bv, bqkv);
  // QKV projection: [2048][2880] @ [5120][2880]^T -> bf16 [2048][5120]; 90 K-tiles
  gemm8p<0><<<dim3(8, 20, 1), 512, 0, stream>>>(Xb, Wqkv, bqkv, QKV, nullptr, NQKV, HIDN, 90);
  rope_kernel<<<(int)(((long)SEQ * 72 * 32 + 255) / 256), 256, 0, stream>>>(QKV, cosb, sinb);
  attn_kernel<<<dim3(SEQ / 64, 64 / 4), 256, 0, stream>>>(QKV, sinks, Ab);
  // O-proj: [2048][4096] @ [3072pad][4096]^T, split-K x2 (64 tiles each) -> fp32 partials
  gemm8p<1><<<dim3(8, 12, 2), 512, 0, stream>>>(Ab, Wot, nullptr, d_out, Pt1, HIDN, 4096, 64);
  combine_out<<<(SEQ * HIDN / 4 + 255) / 256, 256, 0, stream>>>(Pt1, bo, (float*)d_out);
}

// Round 7
// 246.797 us; speedup vs baseline: 1.0643x; 1.0204x over previous
//
#include <hip/hip_runtime.h>

typedef unsigned short u16;
typedef __bf16 bf16x8 __attribute__((ext_vector_type(8)));
typedef float f32x4 __attribute__((ext_vector_type(4)));

// ---- problem constants ----
constexpr int SEQ = 2048;
constexpr int HIDN = 2880;
constexpr int NQKV = 5120;   // 4096 q | 512 k | 512 v
constexpr float SCALE = 0.125f;   // 1/sqrt(64)
constexpr float NEG_INF = -1e30f;

#define ASM_VMCNT(n)  asm volatile("s_waitcnt vmcnt(" #n ")" ::: "memory")
#define ASM_LGKM(n)   asm volatile("s_waitcnt lgkmcnt(" #n ")" ::: "memory")
#define ASM_BARRIER() asm volatile("s_barrier" ::: "memory")
#define SCHEDBAR()    __builtin_amdgcn_sched_barrier(0)

__device__ __forceinline__ u16 f2bf(float f) {
  unsigned int u = __builtin_bit_cast(unsigned int, f);
  u += 0x7FFFu + ((u >> 16) & 1u);
  return (u16)(u >> 16);
}
__device__ __forceinline__ float bf2f(u16 h) {
  unsigned int u = ((unsigned int)h) << 16;
  return __builtin_bit_cast(float, u);
}
__device__ __forceinline__ void async_load16(const void* g, void* l) {
  __builtin_amdgcn_global_load_lds(
      (const __attribute__((address_space(1))) unsigned int*)g,
      (__attribute__((address_space(3))) unsigned int*)l, 16, 0, 0);
}
// asm ds_read_b128: opaque to compiler mem-dep tracking; ordering enforced
// by the volatile waitcnt fences + sched_barrier (rule #18).
__device__ __forceinline__ f32x4 DSR(unsigned addr) {
  f32x4 d;
  asm volatile("ds_read_b128 %0, %1" : "=v"(d) : "v"(addr));
  return d;
}
__device__ __forceinline__ bf16x8 asbf(f32x4 v) { return __builtin_bit_cast(bf16x8, v); }

// ---- fp32 -> bf16 flat convert ----
__global__ __launch_bounds__(256) void conv_f2b(const float* __restrict__ in,
                                                u16* __restrict__ out, long n4) {
  long i = (long)blockIdx.x * 256 + threadIdx.x;
  if (i >= n4) return;
  float4 v = ((const float4*)in)[i];
  u16 o0 = f2bf(v.x), o1 = f2bf(v.y), o2 = f2bf(v.z), o3 = f2bf(v.w);
  out[i * 4 + 0] = o0; out[i * 4 + 1] = o1; out[i * 4 + 2] = o2; out[i * 4 + 3] = o3;
}

// ---- fp32 [R][C] -> bf16 out[c][r] (transpose-convert), dims % 32 == 0 ----
__global__ __launch_bounds__(256) void transpose_f2b(const float* __restrict__ in,
                                                     u16* __restrict__ out,
                                                     int R, int C, int ostride) {
  __shared__ float tile[32][33];
  int c0 = blockIdx.x * 32, r0 = blockIdx.y * 32;
  int tx = threadIdx.x & 31, ty = threadIdx.x >> 5;
#pragma unroll
  for (int i = 0; i < 32; i += 8)
    tile[ty + i][tx] = in[(long)(r0 + ty + i) * C + c0 + tx];
  __syncthreads();
#pragma unroll
  for (int i = 0; i < 32; i += 8)
    out[(long)(c0 + ty + i) * ostride + r0 + tx] = f2bf(tile[tx][ty + i]);
}

__global__ __launch_bounds__(256) void concat_bias(const float* bq, const float* bk,
                                                   const float* bv, float* out) {
  int t = blockIdx.x * 256 + threadIdx.x;
  if (t < 4096) out[t] = bq[t];
  else if (t < 4608) out[t] = bk[t - 4096];
  else if (t < 5120) out[t] = bv[t - 4608];
}

// ======== GEMM: C[M][N] = A[M][K] @ B_t[N][K]^T ========
// BM=128, BN=256, BK=32; 256 thr = 4 waves (1M x 4N), per-wave 128x64
// (12 ds_read / 32 MFMA per K-tile = 0.375). 2 phases/tile, 16 MFMA each.
// LDS: A 3 bufs x 8KB + B 2 bufs x 16KB = 56KB -> 2 blocks/CU co-resident.
// Stage: A(t+2) at P1 (4-phase lead), B(t+2) at P2 (3-phase lead);
// one vmcnt(6) per tile AFTER P2 MFMA (drain overlaps compute).
// Ledger: at that vmcnt, newest 6 = A(t+2)[2]+B(t+2)[4]; everything older
// (incl. A(t+1)@P1(t-1), B(t+1)@P2(t-1)) drains before the barrier that
// precedes P1(t+1)'s ds_reads. WAR: A stage hits buf (t+2)%3 != t%3; B stage
// hits buf(t&1) whose reads completed at P1's closing barrier.
// MODE 0: bf16 out + bias + fused RoPE (cols < 4608). MODE 1: fp32 split-K
// partial (z -> out0/out1), no bias.
template <int MODE>
__global__ __launch_bounds__(256, 2) void gemm_p2(const u16* __restrict__ A,
                                                  const u16* __restrict__ Bp,
                                                  const float* __restrict__ bias,
                                                  const float* __restrict__ cosb,
                                                  const float* __restrict__ sinb,
                                                  void* __restrict__ out0,
                                                  float* __restrict__ out1,
                                                  int N, int Kst, int nkt) {
  __shared__ u16 lds[28672];  // 56KB: A 3x8KB @0 | B 2x16KB @24576
  const int tid = threadIdx.x, lane = tid & 63, wid = tid >> 6;  // wid = n-slice
  const int lr = lane & 15, lk = lane >> 4;

  // T1: bijective XCD swizzle over (x,y)
  const int gm = gridDim.x;
  int nwg = gm * gridDim.y;
  int bid = blockIdx.y * gm + blockIdx.x;
  int q8 = nwg >> 3, r8 = nwg & 7;
  int xcd = bid & 7, seq = bid >> 3;
  int swz = (xcd < r8 ? xcd * (q8 + 1) : r8 * (q8 + 1) + (xcd - r8) * q8) + seq;
  const long brow = (long)(swz % gm) * 128;
  const long bcol = (long)(swz / gm) * 256;
  const long kbase = (MODE == 1) ? (long)blockIdx.z * nkt * 32 : 0;

  char* L = (char*)lds;
  // staging sources, pre-swizzled k-slot = (c&3) ^ ((row>>1)&3), row = c>>2
  const u16* Asrc[2];
  const u16* Bsrc[4];
#pragma unroll
  for (int i = 0; i < 2; ++i) {
    int c = tid + 256 * i;
    Asrc[i] = A + (brow + (c >> 2)) * (long)Kst + kbase + ((c & 3) ^ ((c >> 3) & 3)) * 8;
  }
#pragma unroll
  for (int i = 0; i < 4; ++i) {
    int c = tid + 256 * i;
    Bsrc[i] = Bp + (bcol + (c >> 2)) * (long)Kst + kbase + ((c & 3) ^ ((c >> 3) & 3)) * 8;
  }
  auto stageA = [&](int kt, int ab) {  // 2 loads
    char* d = L + ab * 8192;
    async_load16(Asrc[0] + (long)kt * 32, d + tid * 16);
    async_load16(Asrc[1] + (long)kt * 32, d + (tid + 256) * 16);
  };
  auto stageB = [&](int kt) {          // 4 loads
    char* d = L + 24576 + (kt & 1) * 16384;
#pragma unroll
    for (int i = 0; i < 4; ++i)
      async_load16(Bsrc[i] + (long)kt * 32, d + (tid + 256 * i) * 16);
  };

  // reads: phys slot = lk ^ ((lr>>1)&3) (verified 0-conflict family, R4)
  const unsigned lds0 = (unsigned)(size_t)L;
  const unsigned xs = (unsigned)((lk ^ ((lr >> 1) & 3)) << 4);
  const unsigned aoff = lds0 + (unsigned)(lr * 64) + xs;                        // + abuf*8192 + mf*1024
  const unsigned boff = lds0 + 24576u + (unsigned)((wid * 64 + lr) * 64) + xs;  // + bbuf*16384 + nf*1024

  f32x4 acc[8][4] = {};
  // prologue: tiles 0,1; vmcnt(6) -> tile0 landed (A(1)+B(1)=6 in flight)
  stageA(0, 0); stageB(0); stageA(1, 1); stageB(1);
  ASM_VMCNT(6);
  ASM_BARRIER();

  int a3 = 0;  // t % 3
  for (int t = 0; t < nkt; ++t) {
    const unsigned ab = aoff + (unsigned)(a3 * 8192);
    const unsigned bb = boff + (unsigned)((t & 1) * 16384);
    const bool s2 = (t + 2 < nkt);
    const int a3n = (a3 == 2) ? 0 : a3 + 1;        // (t+1)%3
    const int a3s = (a3n == 2) ? 0 : a3n + 1;      // (t+2)%3
    f32x4 a[4], b[4];
    // ---- P1: reads A lo-half + B, stage A(t+2), MFMA mf0-3 ----
#pragma unroll
    for (int mf = 0; mf < 4; ++mf) a[mf] = DSR(ab + mf * 1024u);
#pragma unroll
    for (int nf = 0; nf < 4; ++nf) b[nf] = DSR(bb + nf * 1024u);
    if (s2) stageA(t + 2, a3s);
    ASM_BARRIER();
    ASM_LGKM(0); SCHEDBAR();
    __builtin_amdgcn_s_setprio(1);
#pragma unroll
    for (int mf = 0; mf < 4; ++mf)
#pragma unroll
      for (int nf = 0; nf < 4; ++nf)
        acc[mf][nf] = __builtin_amdgcn_mfma_f32_16x16x32_bf16(asbf(a[mf]), asbf(b[nf]), acc[mf][nf], 0, 0, 0);
    __builtin_amdgcn_s_setprio(0);
    ASM_BARRIER();
    // ---- P2: reads A hi-half (B reused in regs), stage B(t+2), MFMA mf4-7 ----
#pragma unroll
    for (int mf = 0; mf < 4; ++mf) a[mf] = DSR(ab + (mf + 4) * 1024u);
    if (s2) stageB(t + 2);
    ASM_BARRIER();
    ASM_LGKM(0); SCHEDBAR();
    __builtin_amdgcn_s_setprio(1);
#pragma unroll
    for (int mf = 0; mf < 4; ++mf)
#pragma unroll
      for (int nf = 0; nf < 4; ++nf)
        acc[mf + 4][nf] = __builtin_amdgcn_mfma_f32_16x16x32_bf16(asbf(a[mf]), asbf(b[nf]), acc[mf + 4][nf], 0, 0, 0);
    __builtin_amdgcn_s_setprio(0);
    if (s2) { ASM_VMCNT(6); } else { ASM_VMCNT(0); }
    ASM_BARRIER();
    a3 = a3n;
  }

  // ---- epilogue ----
  const int col0 = (int)bcol + wid * 64;  // wave-uniform head base (64-aligned)
  if (MODE == 0) {
    const bool rope = (col0 < 4608);  // q or k head
#pragma unroll
    for (int mf = 0; mf < 8; ++mf) {
      long row = brow + mf * 16 + lk * 4;
#pragma unroll
      for (int r = 0; r < 4; ++r) {
        long s = row + r;
        if (rope) {
#pragma unroll
          for (int nf = 0; nf < 2; ++nf) {
            int col = col0 + nf * 16 + lr;
            int d = nf * 16 + lr;                 // 0..31 within head
            float c = cosb[s * 64 + d], sn = sinb[s * 64 + d];
            float x1 = acc[mf][nf][r] + bias[col];
            float x2 = acc[mf][nf + 2][r] + bias[col + 32];
            ((u16*)out0)[s * (long)N + col]      = f2bf(x1 * c - x2 * sn);
            ((u16*)out0)[s * (long)N + col + 32] = f2bf(x2 * c + x1 * sn);
          }
        } else {
#pragma unroll
          for (int nf = 0; nf < 4; ++nf) {
            int col = col0 + nf * 16 + lr;
            ((u16*)out0)[s * (long)N + col] = f2bf(acc[mf][nf][r] + bias[col]);
          }
        }
      }
    }
  } else {
    float* o = (blockIdx.z == 0) ? (float*)out0 : out1;
#pragma unroll
    for (int mf = 0; mf < 8; ++mf) {
      long row = brow + mf * 16 + lk * 4;
#pragma unroll
      for (int nf = 0; nf < 4; ++nf) {
        int col = col0 + nf * 16 + lr;
        if (col < N) {
#pragma unroll
          for (int r = 0; r < 4; ++r)
            o[(row + r) * (long)N + col] = acc[mf][nf][r];
        }
      }
    }
  }
}

// ---- combine split-K partials: out = out + P1 + bias ----
__global__ __launch_bounds__(256) void combine_out(const float* __restrict__ P1,
                                                   const float* __restrict__ bias,
                                                   float* __restrict__ out) {
  long i = (long)blockIdx.x * 256 + threadIdx.x;
  if (i >= (long)SEQ * HIDN / 4) return;
  int c4 = (int)(i % (HIDN / 4));
  float4 p0 = ((const float4*)out)[i];
  float4 p1 = ((const float4*)P1)[i];
  float4 b = ((const float4*)bias)[c4];
  float4 r;
  r.x = p0.x + p1.x + b.x; r.y = p0.y + p1.y + b.y;
  r.z = p0.z + p1.z + b.z; r.w = p0.w + p1.w + b.w;
  ((float4*)out)[i] = r;
}

// ---- sliding-window attention with sinks (unchanged) ----
__global__ __launch_bounds__(256, 1) void attn_kernel(const u16* __restrict__ QKV,
                                                      const float* __restrict__ sinks,
                                                      u16* __restrict__ Oa) {
  __shared__ u16 Ks[64 * 64];
  __shared__ u16 Vt[64 * 64];
  __shared__ u16 Ps[4][64 * 72];
  const int tid = threadIdx.x, wid = tid >> 6, lane = tid & 63;
  const int lr = lane & 15, lk = lane >> 4;
  const int i0 = blockIdx.x * 64;
  const int h = blockIdx.y * 4 + wid;
  const int g = h >> 3;

  bf16x8 qf[4][2];
#pragma unroll
  for (int m = 0; m < 4; ++m)
#pragma unroll
    for (int kc = 0; kc < 2; ++kc)
      qf[m][kc] = *(const bf16x8*)&QKV[(long)(i0 + m * 16 + lr) * NQKV + h * 64 + kc * 32 + lk * 8];

  const float sinkh = sinks[h];
  float mrun[4][4], lrun[4][4];
  f32x4 oacc[4][4] = {};
#pragma unroll
  for (int m = 0; m < 4; ++m)
#pragma unroll
    for (int r = 0; r < 4; ++r) { mrun[m][r] = sinkh; lrun[m][r] = 0.f; }

  const int jb0 = (i0 >= 128) ? (i0 - 128) : 0;
  for (int jb = jb0; jb <= i0; jb += 64) {
#pragma unroll
    for (int i = 0; i < 2; ++i) {
      int c = wid * 128 + i * 64 + lane;
      int row = c >> 3, sp = c & 7;
      int ssrc = sp ^ (row & 7);
      async_load16(QKV + (long)(jb + row) * NQKV + 4096 + g * 64 + ssrc * 8,
                   ((char*)Ks) + c * 16);
    }
    {
      int j0 = (tid & 31) * 2, d0 = (tid >> 5) * 8;
      const u16* vp = QKV + (long)(jb + j0) * NQKV + 4608 + g * 64 + d0;
      int4 rv0 = *(const int4*)vp;
      int4 rv1 = *(const int4*)(vp + NQKV);
      const u16* a0 = (const u16*)&rv0;
      const u16* a1 = (const u16*)&rv1;
#pragma unroll
      for (int e = 0; e < 8; ++e) {
        int d = d0 + e;
        unsigned val = (unsigned)a0[e] | ((unsigned)a1[e] << 16);
        int byt = d * 128 + ((((j0 >> 3) ^ (d & 7)) << 4)) + ((j0 & 7) * 2);
        *(unsigned*)((char*)Vt + byt) = val;
      }
    }
    __syncthreads();

    f32x4 sf[4][4] = {};
    __builtin_amdgcn_s_setprio(1);
#pragma unroll
    for (int kc = 0; kc < 2; ++kc) {
      bf16x8 kf[4];
#pragma unroll
      for (int cf = 0; cf < 4; ++cf) {
        int row = cf * 16 + lr;
        kf[cf] = *(const bf16x8*)((const char*)Ks + row * 128 + (((kc * 4 + lk) ^ (lr & 7)) << 4));
      }
#pragma unroll
      for (int m = 0; m < 4; ++m)
#pragma unroll
        for (int cf = 0; cf < 4; ++cf)
          sf[m][cf] = __builtin_amdgcn_mfma_f32_16x16x32_bf16(qf[m][kc], kf[cf], sf[m][cf], 0, 0, 0);
    }
    __builtin_amdgcn_s_setprio(0);

#pragma unroll
    for (int m = 0; m < 4; ++m) {
      float rmax[4];
#pragma unroll
      for (int r = 0; r < 4; ++r) {
        int i = i0 + m * 16 + lk * 4 + r;
        float mx = NEG_INF;
#pragma unroll
        for (int cf = 0; cf < 4; ++cf) {
          int j = jb + cf * 16 + lr;
          float v = sf[m][cf][r] * SCALE;
          bool ok = (j <= i) && (j > i - 128);
          v = ok ? v : NEG_INF;
          sf[m][cf][r] = v;
          mx = fmaxf(mx, v);
        }
#pragma unroll
        for (int off = 1; off < 16; off <<= 1) mx = fmaxf(mx, __shfl_xor(mx, off, 64));
        rmax[r] = mx;
      }
#pragma unroll
      for (int r = 0; r < 4; ++r) {
        float mnew = fmaxf(mrun[m][r], rmax[r]);
        float corr = __expf(mrun[m][r] - mnew);
        mrun[m][r] = mnew;
        float rsum = 0.f;
#pragma unroll
        for (int cf = 0; cf < 4; ++cf) {
          float p = __expf(sf[m][cf][r] - mnew);
          sf[m][cf][r] = p;
          rsum += p;
        }
#pragma unroll
        for (int off = 1; off < 16; off <<= 1) rsum += __shfl_xor(rsum, off, 64);
        lrun[m][r] = lrun[m][r] * corr + rsum;
#pragma unroll
        for (int dn = 0; dn < 4; ++dn) oacc[m][dn][r] *= corr;
      }
    }

#pragma unroll
    for (int m = 0; m < 4; ++m)
#pragma unroll
      for (int cf = 0; cf < 4; ++cf)
#pragma unroll
        for (int r = 0; r < 4; ++r)
          Ps[wid][(m * 16 + lk * 4 + r) * 72 + cf * 16 + lr] = f2bf(sf[m][cf][r]);
    __syncthreads();

    __builtin_amdgcn_s_setprio(1);
#pragma unroll
    for (int kc = 0; kc < 2; ++kc) {
      bf16x8 pf[4], vf[4];
#pragma unroll
      for (int m = 0; m < 4; ++m)
        pf[m] = *(const bf16x8*)&Ps[wid][(m * 16 + lr) * 72 + kc * 32 + lk * 8];
#pragma unroll
      for (int dn = 0; dn < 4; ++dn) {
        int row = dn * 16 + lr;
        vf[dn] = *(const bf16x8*)((const char*)Vt + row * 128 + (((kc * 4 + lk) ^ (lr & 7)) << 4));
      }
#pragma unroll
      for (int m = 0; m < 4; ++m)
#pragma unroll
        for (int dn = 0; dn < 4; ++dn)
          oacc[m][dn] = __builtin_amdgcn_mfma_f32_16x16x32_bf16(pf[m], vf[dn], oacc[m][dn], 0, 0, 0);
    }
    __builtin_amdgcn_s_setprio(0);
    __syncthreads();
  }

#pragma unroll
  for (int m = 0; m < 4; ++m)
#pragma unroll
    for (int r = 0; r < 4; ++r) {
      float denom = lrun[m][r] + __expf(sinkh - mrun[m][r]);
      float inv = 1.f / denom;
      long row = i0 + m * 16 + lk * 4 + r;
#pragma unroll
      for (int dn = 0; dn < 4; ++dn)
        Oa[row * 4096 + h * 64 + dn * 16 + lr] = f2bf(oacc[m][dn][r] * inv);
    }
}

extern "C" void kernel_launch(void* const* d_in, const int* in_sizes, int n_in,
                              void* d_out, int out_size, void* d_ws, size_t ws_size,
                              hipStream_t stream) {
  const float* X    = (const float*)d_in[0];
  const float* cosb = (const float*)d_in[1];
  const float* sinb = (const float*)d_in[2];
  const float* Wq   = (const float*)d_in[3];
  const float* bq   = (const float*)d_in[4];
  const float* Wk   = (const float*)d_in[5];
  const float* bk   = (const float*)d_in[6];
  const float* Wv   = (const float*)d_in[7];
  const float* bv   = (const float*)d_in[8];
  const float* Wo   = (const float*)d_in[9];
  const float* bo   = (const float*)d_in[10];
  const float* sinks = (const float*)d_in[11];

  char* ws = (char*)d_ws;
  size_t off = 0;
  auto alloc = [&](size_t bytes) -> void* {
    void* p = ws + off;
    off += (bytes + 255) & ~(size_t)255;
    return p;
  };
  u16*   Xb    = (u16*)alloc((size_t)SEQ * HIDN * 2);            // [2048][2880]
  u16*   Wqkv  = (u16*)alloc((size_t)NQKV * HIDN * 2);           // [5120][2880]
  u16*   Wot   = (u16*)alloc((size_t)3072 * 4096 * 2);           // [3072][4096] (pad rows)
  float* bqkv  = (float*)alloc((size_t)NQKV * 4);
  u16*   QKV   = (u16*)alloc((size_t)SEQ * NQKV * 2);            // [2048][5120]
  u16*   Ab    = (u16*)alloc((size_t)SEQ * 4096 * 2);            // attn out [2048][4096]
  // split-K partial 1 reuses Wqkv scratch (29.5MB >= 23.6MB; Wqkv dead after QKV GEMM)
  float* Pt1 = (float*)Wqkv;
  (void)ws_size; (void)in_sizes; (void)n_in; (void)out_size;

  conv_f2b<<<(SEQ * HIDN / 4 + 255) / 256, 256, 0, stream>>>(X, Xb, (long)SEQ * HIDN / 4);
  transpose_f2b<<<dim3(4096 / 32, HIDN / 32), 256, 0, stream>>>(Wq, Wqkv, HIDN, 4096, HIDN);
  transpose_f2b<<<dim3(512 / 32, HIDN / 32), 256, 0, stream>>>(Wk, Wqkv + (size_t)4096 * HIDN, HIDN, 512, HIDN);
  transpose_f2b<<<dim3(512 / 32, HIDN / 32), 256, 0, stream>>>(Wv, Wqkv + (size_t)4608 * HIDN, HIDN, 512, HIDN);
  transpose_f2b<<<dim3(HIDN / 32, 4096 / 32), 256, 0, stream>>>(Wo, Wot, 4096, HIDN, 4096);
  concat_bias<<<(NQKV + 255) / 256, 256, 0, stream>>>(bq, bk, bv, bqkv);
  // QKV projection (+bias +fused RoPE): [2048][2880] @ [5120][2880]^T -> bf16 [2048][5120]
  gemm_p2<0><<<dim3(16, 20, 1), 256, 0, stream>>>(Xb, Wqkv, bqkv, cosb, sinb,
                                                  QKV, nullptr, NQKV, HIDN, 90);
  // sliding-window attention with sinks
  attn_kernel<<<dim3(SEQ / 64, 64 / 4), 256, 0, stream>>>(QKV, sinks, Ab);
  // O-proj: [2048][4096] @ [3072pad][4096]^T, split-K x2 (64 tiles each) -> fp32 partials
  gemm_p2<1><<<dim3(16, 12, 2), 256, 0, stream>>>(Ab, Wot, nullptr, nullptr, nullptr,
                                                  d_out, Pt1, HIDN, 4096, 64);
  combine_out<<<(SEQ * HIDN / 4 + 255) / 256, 256, 0, stream>>>(Pt1, bo, (float*)d_out);
}

// Round 8
// 246.309 us; speedup vs baseline: 1.0664x; 1.0020x over previous
//
#include <hip/hip_runtime.h>

typedef unsigned short u16;
typedef __bf16 bf16x8 __attribute__((ext_vector_type(8)));
typedef float f32x4 __attribute__((ext_vector_type(4)));

// ---- problem constants ----
constexpr int SEQ = 2048;
constexpr int HIDN = 2880;
constexpr int NQKV = 5120;   // 4096 q | 512 k | 512 v
constexpr float SCALE = 0.125f;   // 1/sqrt(64)
constexpr float NEG_INF = -1e30f;

#define ASM_VMCNT(n)  asm volatile("s_waitcnt vmcnt(" #n ")" ::: "memory")
#define ASM_LGKM(n)   asm volatile("s_waitcnt lgkmcnt(" #n ")" ::: "memory")
#define ASM_BARRIER() asm volatile("s_barrier" ::: "memory")
#define SCHEDBAR()    __builtin_amdgcn_sched_barrier(0)

__device__ __forceinline__ u16 f2bf(float f) {
  unsigned int u = __builtin_bit_cast(unsigned int, f);
  u += 0x7FFFu + ((u >> 16) & 1u);
  return (u16)(u >> 16);
}
__device__ __forceinline__ float bf2f(u16 h) {
  unsigned int u = ((unsigned int)h) << 16;
  return __builtin_bit_cast(float, u);
}
__device__ __forceinline__ void async_load16(const void* g, void* l) {
  __builtin_amdgcn_global_load_lds(
      (const __attribute__((address_space(1))) unsigned int*)g,
      (__attribute__((address_space(3))) unsigned int*)l, 16, 0, 0);
}
// asm ds_read_b128: opaque to compiler mem-dep tracking; ordering enforced
// by the volatile waitcnt fences + sched_barrier (rule #18).
__device__ __forceinline__ f32x4 DSR(unsigned addr) {
  f32x4 d;
  asm volatile("ds_read_b128 %0, %1" : "=v"(d) : "v"(addr));
  return d;
}
__device__ __forceinline__ bf16x8 asbf(f32x4 v) { return __builtin_bit_cast(bf16x8, v); }

// ---- fp32 -> bf16 flat convert ----
__global__ __launch_bounds__(256) void conv_f2b(const float* __restrict__ in,
                                                u16* __restrict__ out, long n4) {
  long i = (long)blockIdx.x * 256 + threadIdx.x;
  if (i >= n4) return;
  float4 v = ((const float4*)in)[i];
  u16 o0 = f2bf(v.x), o1 = f2bf(v.y), o2 = f2bf(v.z), o3 = f2bf(v.w);
  out[i * 4 + 0] = o0; out[i * 4 + 1] = o1; out[i * 4 + 2] = o2; out[i * 4 + 3] = o3;
}

// ---- merged Wq|Wk|Wv transpose-convert -> Wqkv[5120][2880] bf16 ----
__global__ __launch_bounds__(256) void transpose_qkv(const float* __restrict__ Wq,
                                                     const float* __restrict__ Wk,
                                                     const float* __restrict__ Wv,
                                                     u16* __restrict__ out) {
  __shared__ float tile[32][33];
  int c0 = blockIdx.x * 32, r0 = blockIdx.y * 32;   // c0: qkv col, r0: hid row
  int tx = threadIdx.x & 31, ty = threadIdx.x >> 5;
  const float* src; int C, cl;
  if (c0 < 4096)      { src = Wq; C = 4096; cl = c0; }
  else if (c0 < 4608) { src = Wk; C = 512;  cl = c0 - 4096; }
  else                { src = Wv; C = 512;  cl = c0 - 4608; }
#pragma unroll
  for (int i = 0; i < 32; i += 8)
    tile[ty + i][tx] = src[(long)(r0 + ty + i) * C + cl + tx];
  __syncthreads();
#pragma unroll
  for (int i = 0; i < 32; i += 8)
    out[(long)(c0 + ty + i) * HIDN + r0 + tx] = f2bf(tile[tx][ty + i]);
}

// ---- fp32 [R][C] -> bf16 out[c][r] (transpose-convert), dims % 32 == 0 ----
__global__ __launch_bounds__(256) void transpose_f2b(const float* __restrict__ in,
                                                     u16* __restrict__ out,
                                                     int R, int C, int ostride) {
  __shared__ float tile[32][33];
  int c0 = blockIdx.x * 32, r0 = blockIdx.y * 32;
  int tx = threadIdx.x & 31, ty = threadIdx.x >> 5;
#pragma unroll
  for (int i = 0; i < 32; i += 8)
    tile[ty + i][tx] = in[(long)(r0 + ty + i) * C + c0 + tx];
  __syncthreads();
#pragma unroll
  for (int i = 0; i < 32; i += 8)
    out[(long)(c0 + ty + i) * ostride + r0 + tx] = f2bf(tile[tx][ty + i]);
}

__global__ __launch_bounds__(256) void concat_bias(const float* bq, const float* bk,
                                                   const float* bv, float* out) {
  int t = blockIdx.x * 256 + threadIdx.x;
  if (t < 4096) out[t] = bq[t];
  else if (t < 4608) out[t] = bk[t - 4096];
  else if (t < 5120) out[t] = bv[t - 4608];
}

// ======== GEMM: C[M][N] = A[M][K] @ B_t[N][K]^T ========
// BM=256, BN=256, BK=32; 512 thr = 8 waves (2M x 4N), per-wave 128x64
// (12 ds_read / 32 MFMA per K-tile). 2 phases/tile, 16 MFMA each, B-frags
// register-reused across both phases.
// LDS 80KB: A 3 bufs x 16KB @0 | B 2 bufs x 16KB @49152. 1 block/CU, 8 waves.
// Schedule per tile t: P1{read A-lo(4)+B(4), stage A(t+2), bar, lgkm0,
// 16 MFMA, bar}; P2{read A-hi(4), stage B(t+2), bar, lgkm0, 16 MFMA,
// vmcnt(4), bar}.
// Ledger: end-of-tile vmcnt(4) leaves only A(t+2)+B(t+2) in flight => tile
// t+1 landed. WAR(A): stage hits buf (t+2)%3, reads use t%3; last reader of
// (t-1)%3 finished a barrier ago. WAR(B): buf (t+2)&1 == t&1, but all B
// reads of tile t completed before P1's closing barrier (lgkm0 precedes it),
// and stageB is issued after that barrier.
// MODE 0: bf16 out + bias + fused RoPE (cols < 4608). MODE 1: fp32 split-K
// partial (z -> out0/out1), no bias.
template <int MODE>
__global__ __launch_bounds__(512, 2) void gemm_8w(const u16* __restrict__ A,
                                                  const u16* __restrict__ Bp,
                                                  const float* __restrict__ bias,
                                                  const float* __restrict__ cosb,
                                                  const float* __restrict__ sinb,
                                                  void* __restrict__ out0,
                                                  float* __restrict__ out1,
                                                  int N, int Kst, int nkt) {
  __shared__ u16 lds[40960];  // 80KB
  const int tid = threadIdx.x, lane = tid & 63, wid = tid >> 6;
  const int wm = wid >> 2, wn = wid & 3;
  const int lr = lane & 15, lk = lane >> 4;

  // T1: bijective XCD swizzle over (x,y)
  const int gm = gridDim.x;
  int nwg = gm * gridDim.y;
  int bid = blockIdx.y * gm + blockIdx.x;
  int q8 = nwg >> 3, r8 = nwg & 7;
  int xcd = bid & 7, seq = bid >> 3;
  int swz = (xcd < r8 ? xcd * (q8 + 1) : r8 * (q8 + 1) + (xcd - r8) * q8) + seq;
  const long brow = (long)(swz % gm) * 256;
  const long bcol = (long)(swz / gm) * 256;
  const long kbase = (MODE == 1) ? (long)blockIdx.z * nkt * 32 : 0;

  char* L = (char*)lds;
  // staging sources, pre-swizzled k-slot = (c&3) ^ ((row>>1)&3), row = c>>2
  const u16* Asrc[2];
  const u16* Bsrc[2];
#pragma unroll
  for (int i = 0; i < 2; ++i) {
    int c = tid + 512 * i;
    long ks = kbase + ((c & 3) ^ ((c >> 3) & 3)) * 8;
    Asrc[i] = A  + (brow + (c >> 2)) * (long)Kst + ks;
    Bsrc[i] = Bp + (bcol + (c >> 2)) * (long)Kst + ks;
  }
  auto stageA = [&](int kt, int ab) {  // 2 loads/thread
    char* d = L + ab * 16384;
    async_load16(Asrc[0] + (long)kt * 32, d + tid * 16);
    async_load16(Asrc[1] + (long)kt * 32, d + (tid + 512) * 16);
  };
  auto stageB = [&](int kt, int bb) {  // 2 loads/thread
    char* d = L + 49152 + bb * 16384;
    async_load16(Bsrc[0] + (long)kt * 32, d + tid * 16);
    async_load16(Bsrc[1] + (long)kt * 32, d + (tid + 512) * 16);
  };

  // reads: phys slot = lk ^ ((lr>>1)&3) (verified 0-conflict family, R4)
  const unsigned lds0 = (unsigned)(size_t)L;
  const unsigned xs = (unsigned)((lk ^ ((lr >> 1) & 3)) << 4);
  const unsigned aoff = lds0 + (unsigned)((wm * 128 + lr) * 64) + xs;           // + abuf*16384 + mf*1024
  const unsigned boff = lds0 + 49152u + (unsigned)((wn * 64 + lr) * 64) + xs;   // + bbuf*16384 + nf*1024

  f32x4 acc[8][4] = {};
  // prologue: tiles 0,1; vmcnt(4) -> tile0 landed (A1,B1 may fly)
  stageA(0, 0); stageB(0, 0); stageA(1, 1); stageB(1, 1);
  ASM_VMCNT(4);
  ASM_BARRIER();

  int a3 = 0;  // t % 3
  for (int t = 0; t < nkt; ++t) {
    const unsigned ab = aoff + (unsigned)(a3 * 16384);
    const unsigned bb = boff + (unsigned)((t & 1) * 16384);
    const bool s2 = (t + 2 < nkt);
    const int a3n = (a3 == 2) ? 0 : a3 + 1;        // (t+1)%3
    const int a3s = (a3n == 2) ? 0 : a3n + 1;      // (t+2)%3
    f32x4 a[4], b[4];
    // ---- P1: read A-lo + B, stage A(t+2), MFMA mf0-3 ----
#pragma unroll
    for (int mf = 0; mf < 4; ++mf) a[mf] = DSR(ab + mf * 1024u);
#pragma unroll
    for (int nf = 0; nf < 4; ++nf) b[nf] = DSR(bb + nf * 1024u);
    if (s2) stageA(t + 2, a3s);
    ASM_BARRIER();
    ASM_LGKM(0); SCHEDBAR();
    __builtin_amdgcn_s_setprio(1);
#pragma unroll
    for (int mf = 0; mf < 4; ++mf)
#pragma unroll
      for (int nf = 0; nf < 4; ++nf)
        acc[mf][nf] = __builtin_amdgcn_mfma_f32_16x16x32_bf16(asbf(a[mf]), asbf(b[nf]), acc[mf][nf], 0, 0, 0);
    __builtin_amdgcn_s_setprio(0);
    ASM_BARRIER();
    // ---- P2: read A-hi (B reused in regs), stage B(t+2), MFMA mf4-7 ----
#pragma unroll
    for (int mf = 0; mf < 4; ++mf) a[mf] = DSR(ab + (mf + 4) * 1024u);
    if (s2) stageB(t + 2, t & 1);
    ASM_BARRIER();
    ASM_LGKM(0); SCHEDBAR();
    __builtin_amdgcn_s_setprio(1);
#pragma unroll
    for (int mf = 0; mf < 4; ++mf)
#pragma unroll
      for (int nf = 0; nf < 4; ++nf)
        acc[mf + 4][nf] = __builtin_amdgcn_mfma_f32_16x16x32_bf16(asbf(a[mf]), asbf(b[nf]), acc[mf + 4][nf], 0, 0, 0);
    __builtin_amdgcn_s_setprio(0);
    if (s2) { ASM_VMCNT(4); } else { ASM_VMCNT(0); }
    ASM_BARRIER();
    a3 = a3n;
  }

  // ---- epilogue ----
  const int col0 = (int)bcol + wn * 64;  // wave-uniform head base (64-aligned)
  if (MODE == 0) {
    const bool rope = (col0 < 4608);  // q or k head
#pragma unroll
    for (int mf = 0; mf < 8; ++mf) {
      long row = brow + wm * 128 + mf * 16 + lk * 4;
#pragma unroll
      for (int r = 0; r < 4; ++r) {
        long s = row + r;
        if (rope) {
#pragma unroll
          for (int nf = 0; nf < 2; ++nf) {
            int col = col0 + nf * 16 + lr;
            int d = nf * 16 + lr;                 // 0..31 within head
            float c = cosb[s * 64 + d], sn = sinb[s * 64 + d];
            float x1 = acc[mf][nf][r] + bias[col];
            float x2 = acc[mf][nf + 2][r] + bias[col + 32];
            ((u16*)out0)[s * (long)N + col]      = f2bf(x1 * c - x2 * sn);
            ((u16*)out0)[s * (long)N + col + 32] = f2bf(x2 * c + x1 * sn);
          }
        } else {
#pragma unroll
          for (int nf = 0; nf < 4; ++nf) {
            int col = col0 + nf * 16 + lr;
            ((u16*)out0)[s * (long)N + col] = f2bf(acc[mf][nf][r] + bias[col]);
          }
        }
      }
    }
  } else {
    float* o = (blockIdx.z == 0) ? (float*)out0 : out1;
#pragma unroll
    for (int mf = 0; mf < 8; ++mf) {
      long row = brow + wm * 128 + mf * 16 + lk * 4;
#pragma unroll
      for (int nf = 0; nf < 4; ++nf) {
        int col = col0 + nf * 16 + lr;
        if (col < N) {
#pragma unroll
          for (int r = 0; r < 4; ++r)
            o[(row + r) * (long)N + col] = acc[mf][nf][r];
        }
      }
    }
  }
}

// ---- combine split-K partials: out = out + P1 + bias ----
__global__ __launch_bounds__(256) void combine_out(const float* __restrict__ P1,
                                                   const float* __restrict__ bias,
                                                   float* __restrict__ out) {
  long i = (long)blockIdx.x * 256 + threadIdx.x;
  if (i >= (long)SEQ * HIDN / 4) return;
  int c4 = (int)(i % (HIDN / 4));
  float4 p0 = ((const float4*)out)[i];
  float4 p1 = ((const float4*)P1)[i];
  float4 b = ((const float4*)bias)[c4];
  float4 r;
  r.x = p0.x + p1.x + b.x; r.y = p0.y + p1.y + b.y;
  r.z = p0.z + p1.z + b.z; r.w = p0.w + p1.w + b.w;
  ((float4*)out)[i] = r;
}

// ---- sliding-window attention with sinks (unchanged) ----
__global__ __launch_bounds__(256, 1) void attn_kernel(const u16* __restrict__ QKV,
                                                      const float* __restrict__ sinks,
                                                      u16* __restrict__ Oa) {
  __shared__ u16 Ks[64 * 64];
  __shared__ u16 Vt[64 * 64];
  __shared__ u16 Ps[4][64 * 72];
  const int tid = threadIdx.x, wid = tid >> 6, lane = tid & 63;
  const int lr = lane & 15, lk = lane >> 4;
  const int i0 = blockIdx.x * 64;
  const int h = blockIdx.y * 4 + wid;
  const int g = h >> 3;

  bf16x8 qf[4][2];
#pragma unroll
  for (int m = 0; m < 4; ++m)
#pragma unroll
    for (int kc = 0; kc < 2; ++kc)
      qf[m][kc] = *(const bf16x8*)&QKV[(long)(i0 + m * 16 + lr) * NQKV + h * 64 + kc * 32 + lk * 8];

  const float sinkh = sinks[h];
  float mrun[4][4], lrun[4][4];
  f32x4 oacc[4][4] = {};
#pragma unroll
  for (int m = 0; m < 4; ++m)
#pragma unroll
    for (int r = 0; r < 4; ++r) { mrun[m][r] = sinkh; lrun[m][r] = 0.f; }

  const int jb0 = (i0 >= 128) ? (i0 - 128) : 0;
  for (int jb = jb0; jb <= i0; jb += 64) {
#pragma unroll
    for (int i = 0; i < 2; ++i) {
      int c = wid * 128 + i * 64 + lane;
      int row = c >> 3, sp = c & 7;
      int ssrc = sp ^ (row & 7);
      async_load16(QKV + (long)(jb + row) * NQKV + 4096 + g * 64 + ssrc * 8,
                   ((char*)Ks) + c * 16);
    }
    {
      int j0 = (tid & 31) * 2, d0 = (tid >> 5) * 8;
      const u16* vp = QKV + (long)(jb + j0) * NQKV + 4608 + g * 64 + d0;
      int4 rv0 = *(const int4*)vp;
      int4 rv1 = *(const int4*)(vp + NQKV);
      const u16* a0 = (const u16*)&rv0;
      const u16* a1 = (const u16*)&rv1;
#pragma unroll
      for (int e = 0; e < 8; ++e) {
        int d = d0 + e;
        unsigned val = (unsigned)a0[e] | ((unsigned)a1[e] << 16);
        int byt = d * 128 + ((((j0 >> 3) ^ (d & 7)) << 4)) + ((j0 & 7) * 2);
        *(unsigned*)((char*)Vt + byt) = val;
      }
    }
    __syncthreads();

    f32x4 sf[4][4] = {};
    __builtin_amdgcn_s_setprio(1);
#pragma unroll
    for (int kc = 0; kc < 2; ++kc) {
      bf16x8 kf[4];
#pragma unroll
      for (int cf = 0; cf < 4; ++cf) {
        int row = cf * 16 + lr;
        kf[cf] = *(const bf16x8*)((const char*)Ks + row * 128 + (((kc * 4 + lk) ^ (lr & 7)) << 4));
      }
#pragma unroll
      for (int m = 0; m < 4; ++m)
#pragma unroll
        for (int cf = 0; cf < 4; ++cf)
          sf[m][cf] = __builtin_amdgcn_mfma_f32_16x16x32_bf16(qf[m][kc], kf[cf], sf[m][cf], 0, 0, 0);
    }
    __builtin_amdgcn_s_setprio(0);

#pragma unroll
    for (int m = 0; m < 4; ++m) {
      float rmax[4];
#pragma unroll
      for (int r = 0; r < 4; ++r) {
        int i = i0 + m * 16 + lk * 4 + r;
        float mx = NEG_INF;
#pragma unroll
        for (int cf = 0; cf < 4; ++cf) {
          int j = jb + cf * 16 + lr;
          float v = sf[m][cf][r] * SCALE;
          bool ok = (j <= i) && (j > i - 128);
          v = ok ? v : NEG_INF;
          sf[m][cf][r] = v;
          mx = fmaxf(mx, v);
        }
#pragma unroll
        for (int off = 1; off < 16; off <<= 1) mx = fmaxf(mx, __shfl_xor(mx, off, 64));
        rmax[r] = mx;
      }
#pragma unroll
      for (int r = 0; r < 4; ++r) {
        float mnew = fmaxf(mrun[m][r], rmax[r]);
        float corr = __expf(mrun[m][r] - mnew);
        mrun[m][r] = mnew;
        float rsum = 0.f;
#pragma unroll
        for (int cf = 0; cf < 4; ++cf) {
          float p = __expf(sf[m][cf][r] - mnew);
          sf[m][cf][r] = p;
          rsum += p;
        }
#pragma unroll
        for (int off = 1; off < 16; off <<= 1) rsum += __shfl_xor(rsum, off, 64);
        lrun[m][r] = lrun[m][r] * corr + rsum;
#pragma unroll
        for (int dn = 0; dn < 4; ++dn) oacc[m][dn][r] *= corr;
      }
    }

#pragma unroll
    for (int m = 0; m < 4; ++m)
#pragma unroll
      for (int cf = 0; cf < 4; ++cf)
#pragma unroll
        for (int r = 0; r < 4; ++r)
          Ps[wid][(m * 16 + lk * 4 + r) * 72 + cf * 16 + lr] = f2bf(sf[m][cf][r]);
    __syncthreads();

    __builtin_amdgcn_s_setprio(1);
#pragma unroll
    for (int kc = 0; kc < 2; ++kc) {
      bf16x8 pf[4], vf[4];
#pragma unroll
      for (int m = 0; m < 4; ++m)
        pf[m] = *(const bf16x8*)&Ps[wid][(m * 16 + lr) * 72 + kc * 32 + lk * 8];
#pragma unroll
      for (int dn = 0; dn < 4; ++dn) {
        int row = dn * 16 + lr;
        vf[dn] = *(const bf16x8*)((const char*)Vt + row * 128 + (((kc * 4 + lk) ^ (lr & 7)) << 4));
      }
#pragma unroll
      for (int m = 0; m < 4; ++m)
#pragma unroll
        for (int dn = 0; dn < 4; ++dn)
          oacc[m][dn] = __builtin_amdgcn_mfma_f32_16x16x32_bf16(pf[m], vf[dn], oacc[m][dn], 0, 0, 0);
    }
    __builtin_amdgcn_s_setprio(0);
    __syncthreads();
  }

#pragma unroll
  for (int m = 0; m < 4; ++m)
#pragma unroll
    for (int r = 0; r < 4; ++r) {
      float denom = lrun[m][r] + __expf(sinkh - mrun[m][r]);
      float inv = 1.f / denom;
      long row = i0 + m * 16 + lk * 4 + r;
#pragma unroll
      for (int dn = 0; dn < 4; ++dn)
        Oa[row * 4096 + h * 64 + dn * 16 + lr] = f2bf(oacc[m][dn][r] * inv);
    }
}

extern "C" void kernel_launch(void* const* d_in, const int* in_sizes, int n_in,
                              void* d_out, int out_size, void* d_ws, size_t ws_size,
                              hipStream_t stream) {
  const float* X    = (const float*)d_in[0];
  const float* cosb = (const float*)d_in[1];
  const float* sinb = (const float*)d_in[2];
  const float* Wq   = (const float*)d_in[3];
  const float* bq   = (const float*)d_in[4];
  const float* Wk   = (const float*)d_in[5];
  const float* bk   = (const float*)d_in[6];
  const float* Wv   = (const float*)d_in[7];
  const float* bv   = (const float*)d_in[8];
  const float* Wo   = (const float*)d_in[9];
  const float* bo   = (const float*)d_in[10];
  const float* sinks = (const float*)d_in[11];

  char* ws = (char*)d_ws;
  size_t off = 0;
  auto alloc = [&](size_t bytes) -> void* {
    void* p = ws + off;
    off += (bytes + 255) & ~(size_t)255;
    return p;
  };
  u16*   Xb    = (u16*)alloc((size_t)SEQ * HIDN * 2);            // [2048][2880]
  u16*   Wqkv  = (u16*)alloc((size_t)NQKV * HIDN * 2);           // [5120][2880]
  u16*   Wot   = (u16*)alloc((size_t)3072 * 4096 * 2);           // [3072][4096] (pad rows)
  float* bqkv  = (float*)alloc((size_t)NQKV * 4);
  u16*   QKV   = (u16*)alloc((size_t)SEQ * NQKV * 2);            // [2048][5120]
  u16*   Ab    = (u16*)alloc((size_t)SEQ * 4096 * 2);            // attn out [2048][4096]
  // split-K partial 1 reuses Wqkv scratch (29.5MB >= 23.6MB; Wqkv dead after QKV GEMM)
  float* Pt1 = (float*)Wqkv;
  (void)ws_size; (void)in_sizes; (void)n_in; (void)out_size;

  conv_f2b<<<(SEQ * HIDN / 4 + 255) / 256, 256, 0, stream>>>(X, Xb, (long)SEQ * HIDN / 4);
  transpose_qkv<<<dim3(NQKV / 32, HIDN / 32), 256, 0, stream>>>(Wq, Wk, Wv, Wqkv);
  transpose_f2b<<<dim3(HIDN / 32, 4096 / 32), 256, 0, stream>>>(Wo, Wot, 4096, HIDN, 4096);
  concat_bias<<<(NQKV + 255) / 256, 256, 0, stream>>>(bq, bk, bv, bqkv);
  // QKV projection (+bias +fused RoPE): [2048][2880] @ [5120][2880]^T -> bf16 [2048][5120]
  gemm_8w<0><<<dim3(8, 20, 1), 512, 0, stream>>>(Xb, Wqkv, bqkv, cosb, sinb,
                                                 QKV, nullptr, NQKV, HIDN, 90);
  // sliding-window attention with sinks
  attn_kernel<<<dim3(SEQ / 64, 64 / 4), 256, 0, stream>>>(QKV, sinks, Ab);
  // O-proj: [2048][4096] @ [3072pad][4096]^T, split-K x2 (64 tiles each) -> fp32 partials
  gemm_8w<1><<<dim3(8, 12, 2), 512, 0, stream>>>(Ab, Wot, nullptr, nullptr, nullptr,
                                                 d_out, Pt1, HIDN, 4096, 64);
  combine_out<<<(SEQ * HIDN / 4 + 255) / 256, 256, 0, stream>>>(Pt1, bo, (float*)d_out);
}